// Round 7
// baseline (273.290 us; speedup 1.0000x reference)
//
#include <hip/hip_runtime.h>
#include <hip/hip_bf16.h>
#include <math.h>

#define SEQ 2048

typedef __bf16 bf16x8 __attribute__((ext_vector_type(8)));
typedef float  f32x4  __attribute__((ext_vector_type(4)));

#if __has_builtin(__builtin_amdgcn_exp2f)
#define EXP2(x) __builtin_amdgcn_exp2f(x)
#else
#define EXP2(x) exp2f(x)
#endif

__device__ __forceinline__ unsigned short f2bf(float f) {
  __bf16 h = (__bf16)f;
  return __builtin_bit_cast(unsigned short, h);
}

__device__ __forceinline__ void gload16(const unsigned short* g, unsigned short* l) {
  __builtin_amdgcn_global_load_lds(
      (const __attribute__((address_space(1))) void*)g,
      (__attribute__((address_space(3))) void*)l, 16, 0, 0);
}

// packed f32->bf16 convert (RNE, same rounding as scalar (__bf16) cast)
__device__ __forceinline__ unsigned cvtpk(float lo, float hi) {
  unsigned r;
  asm("v_cvt_pk_bf16_f32 %0, %1, %2" : "=v"(r) : "v"(lo), "v"(hi));
  return r;
}
// a[32:63] <-> b[0:31]:  a' = [a_q0,a_q1,b_q0,b_q1], b' = [a_q2,a_q3,b_q2,b_q3]
__device__ __forceinline__ void plswap32(unsigned &a, unsigned &b) {
  asm("v_permlane32_swap_b32 %0, %1" : "+v"(a), "+v"(b));
}
// odd 16-rows of a <-> even 16-rows of b: a' = [a0,b0,a2,b2], b' = [a1,b1,a3,b3]
__device__ __forceinline__ void plswap16(unsigned &a, unsigned &b) {
  asm("v_permlane16_swap_b32 %0, %1" : "+v"(a), "+v"(b));
}

#define CLOG (0.125f * 1.44269504f)   // 1/sqrt(HD) * log2(e), folded into q

// ============ mega prep kernel: rope cos/sin table + 8 weight transposes ============
struct WPrep {
  const float* src[8];
  unsigned short* dst[8];
  int K[8], N[8], NR[8], KC[8], nb[8];
  float2* cst;
};

__global__ __launch_bounds__(256) void wprep_kernel(WPrep p)
{
  __shared__ float tile[32][33];
  int bid = blockIdx.x;
  if (bid < 128) {                       // rope table: 32768 entries
    const int idx = bid * 256 + threadIdx.x;
    const int pos = idx >> 4, i = idx & 15;
    const float freq = EXP2(-(float)i * 0.8304820237f);
    const float ang = (float)pos * freq;
    p.cst[idx] = make_float2(cosf(ang), sinf(ang));
    return;
  }
  bid -= 128;
  int di = 0;
  while (bid >= p.nb[di]) { bid -= p.nb[di]; ++di; }
  const float* src = p.src[di];
  unsigned short* dst = p.dst[di];
  const int K = p.K[di], N = p.N[di], KC = p.KC[di];
  const int nkx = KC >> 5;
  const int k0 = (bid % nkx) * 32, n0 = (bid / nkx) * 32;
  const int tx = threadIdx.x & 31, ty = threadIdx.x >> 5;
  for (int r = ty; r < 32; r += 8) {
    const int k = k0 + r, n = n0 + tx;
    tile[r][tx] = (k < K && n < N) ? src[(long)k * N + n] : 0.0f;
  }
  __syncthreads();
  for (int r = ty; r < 32; r += 8) {
    const int n = n0 + r, k = k0 + tx;
    dst[(long)n * KC + k] = f2bf(tile[tx][r]);
  }
}

// ============ 128-tile bf16 MFMA GEMM body (for wide-N, short-K GEMMs) ============
// EPI: 3 QROPE: cols<512 -> qn (*CLOG); cols>=512 rope -> qr (*CLOG)   [stride 512]
//      5 KNV:   cols<512 -> kn (stride 512); cols>=512 -> vT (B,H,64,S) via LDS transpose
template <int EPI, bool AF32>
__device__ __forceinline__ void gemm_body(
    unsigned short* smem,                     // 16896 shorts
    const void* __restrict__ Av, const unsigned short* __restrict__ BT,
    const float* __restrict__ bias, const float2* __restrict__ cst,
    void* __restrict__ C0v, void* __restrict__ C1v, int K, int N,
    int bx, int by)
{
  unsigned short* As = smem;               // [2][128*32]
  unsigned short* Bs = smem + 2 * 128 * 32;
  const int tid = threadIdx.x;
  const int w = tid >> 6, lane = tid & 63;
  const int ln16 = lane & 15, quad = lane >> 4;
  const int wm = (w >> 1) * 64, wn = (w & 1) * 64;
  const int m0 = by * 128, n0 = bx * 128;
  const int rr = tid >> 2, cc = (tid & 3) * 8;

  const unsigned short* A = (const unsigned short*)Av;

  auto stageB = [&](int ib, int k0) {
    gload16(&BT[(long)(n0 + rr)      * K + k0 + cc], &Bs[ib * 4096 + rr * 32 + cc]);
    gload16(&BT[(long)(n0 + 64 + rr) * K + k0 + cc], &Bs[ib * 4096 + (64 + rr) * 32 + cc]);
  };
  auto stageAbf = [&](int ib, int k0) {
    gload16(&A[(long)(m0 + rr)      * K + k0 + cc], &As[ib * 4096 + rr * 32 + cc]);
    gload16(&A[(long)(m0 + 64 + rr) * K + k0 + cc], &As[ib * 4096 + (64 + rr) * 32 + cc]);
  };

  f32x4 acc[4][4];
#pragma unroll
  for (int i = 0; i < 4; ++i)
#pragma unroll
    for (int j = 0; j < 4; ++j)
#pragma unroll
      for (int r = 0; r < 4; ++r) acc[i][j][r] = 0.0f;

  stageB(0, 0);
  stageAbf(0, 0);

  int ib = 0;
  for (int k0 = 0; k0 < K; k0 += 32, ib ^= 1) {
    __syncthreads();
    const int kn = k0 + 32;
    if (kn < K) { stageB(ib ^ 1, kn); stageAbf(ib ^ 1, kn); }
    bf16x8 fa[4], fb[4];
#pragma unroll
    for (int i = 0; i < 4; ++i) fa[i] = *(const bf16x8*)&As[ib * 4096 + (wm + i * 16 + ln16) * 32 + quad * 8];
#pragma unroll
    for (int j = 0; j < 4; ++j) fb[j] = *(const bf16x8*)&Bs[ib * 4096 + (wn + j * 16 + ln16) * 32 + quad * 8];
#pragma unroll
    for (int i = 0; i < 4; ++i)
#pragma unroll
      for (int j = 0; j < 4; ++j)
        acc[i][j] = __builtin_amdgcn_mfma_f32_16x16x32_bf16(fa[i], fb[j], acc[i][j], 0, 0, 0);
  }

  // ----- epilogues -----
  if (EPI == 5 && n0 >= 512) {
    // fused V transpose: acc tile (128 s-rows x 128 cols) -> vT (B,H,64,S) coalesced
    __syncthreads();
#pragma unroll
    for (int i = 0; i < 4; ++i) {
      const int rl = wm + i * 16 + quad * 4;
#pragma unroll
      for (int j = 0; j < 4; ++j) {
        const int cl = wn + j * 16 + ln16;
        ushort4 u;
        u.x = f2bf(acc[i][j][0]); u.y = f2bf(acc[i][j][1]);
        u.z = f2bf(acc[i][j][2]); u.w = f2bf(acc[i][j][3]);
        *(ushort4*)&smem[cl * 132 + rl] = u;
      }
    }
    __syncthreads();
    unsigned short* vT = (unsigned short*)C1v;
    const int b = m0 >> 11, sbase = m0 & (SEQ - 1);
    for (int q = tid; q < 128 * 16; q += 256) {
      const int cl = q >> 4, sch = (q & 15) * 8;
      bf16x8 val = *(const bf16x8*)&smem[cl * 132 + sch];
      const int c = (n0 - 512) + cl;
      const int hh = c >> 6, dd = c & 63;
      *(bf16x8*)&vT[((long)(b * 16 + hh) * 64 + dd) * SEQ + sbase + sch] = val;
    }
    return;
  }
#pragma unroll
  for (int i = 0; i < 4; ++i) {
    const int row0 = m0 + wm + i * 16 + quad * 4;
#pragma unroll
    for (int j = 0; j < 4; ++j) {
      const int col = n0 + wn + j * 16 + ln16;
      if (EPI == 3) {
        if (n0 < 512) {
          unsigned short* qn = (unsigned short*)C0v;
#pragma unroll
          for (int r = 0; r < 4; ++r) qn[(long)(row0 + r) * 512 + col] = f2bf(acc[i][j][r] * CLOG);
        } else {
          unsigned short* qr = (unsigned short*)C1v;
          const int c = col - 512;
          const int d = c & 31;
#pragma unroll
          for (int r = 0; r < 4; ++r) {
            const float v = acc[i][j][r];
            const float p = __shfl_xor(v, 1);
            const float2 t = cst[((row0 + r) & (SEQ - 1)) * 16 + (d >> 1)];
            const float o = ((d & 1) == 0) ? (v * t.x - p * t.y) : (p * t.y + v * t.x);
            qr[(long)(row0 + r) * 512 + c] = f2bf(o * CLOG);
          }
        }
      } else if (EPI == 5) {
        unsigned short* kn = (unsigned short*)C0v;
#pragma unroll
        for (int r = 0; r < 4; ++r) kn[(long)(row0 + r) * 512 + col] = f2bf(acc[i][j][r]);
      }
    }
  }
}

// dual 128-tile wrapper
template <int E0, bool AF0, int E1, bool AF1>
__global__ __launch_bounds__(256) void gemm_dual(
    const void* __restrict__ A0, const unsigned short* __restrict__ BT0,
    void* __restrict__ C00, void* __restrict__ C01, int K0, int N0, int nx0,
    const void* __restrict__ A1, const unsigned short* __restrict__ BT1,
    void* __restrict__ C10, void* __restrict__ C11, int K1, int N1,
    const float2* __restrict__ cst)
{
  __shared__ unsigned short smem[16896];
  if (blockIdx.z == 0) {
    if ((int)blockIdx.x >= nx0) return;
    gemm_body<E0, AF0>(smem, A0, BT0, nullptr, cst, C00, C01, K0, N0, blockIdx.x, blockIdx.y);
  } else {
    gemm_body<E1, AF1>(smem, A1, BT1, nullptr, cst, C10, C11, K1, N1, blockIdx.x, blockIdx.y);
  }
}

// ============ 64-tile bf16 MFMA GEMM body (for deep-K GEMMs: more blocks = TLP) =====
// EPI: 0 f32->C0 ; 1 f32+bias->C0 ; 4 KVKR: cols<256 f32->kvl ; cols 256..287 rope/16->kr
template <int EPI, bool AF32>
__device__ __forceinline__ void gemm_body64(
    unsigned short* smem,                     // 8192 shorts
    const void* __restrict__ Av, const unsigned short* __restrict__ BT,
    const float* __restrict__ bias, const float2* __restrict__ cst,
    void* __restrict__ C0v, void* __restrict__ C1v, int K, int N,
    int bx, int by)
{
  unsigned short* As = smem;               // [2][64*32]
  unsigned short* Bs = smem + 2 * 64 * 32;
  const int tid = threadIdx.x;
  const int w = tid >> 6, lane = tid & 63;
  const int ln16 = lane & 15, quad = lane >> 4;
  const int wm = (w >> 1) * 32, wn = (w & 1) * 32;
  const int m0 = by * 64, n0 = bx * 64;
  const int rr = tid >> 2, cc = (tid & 3) * 8;

  const unsigned short* A = (const unsigned short*)Av;
  const float* Af = (const float*)Av;

  auto stageB = [&](int ib, int k0) {
    gload16(&BT[(long)(n0 + rr) * K + k0 + cc], &Bs[ib * 2048 + rr * 32 + cc]);
  };
  auto stageAbf = [&](int ib, int k0) {
    gload16(&A[(long)(m0 + rr) * K + k0 + cc], &As[ib * 2048 + rr * 32 + cc]);
  };
  auto writeAf32 = [&](int ib, const float4& a0, const float4& a1) {
    ushort4 u;
    u.x = f2bf(a0.x); u.y = f2bf(a0.y); u.z = f2bf(a0.z); u.w = f2bf(a0.w);
    *(ushort4*)&As[ib * 2048 + rr * 32 + cc] = u;
    u.x = f2bf(a1.x); u.y = f2bf(a1.y); u.z = f2bf(a1.z); u.w = f2bf(a1.w);
    *(ushort4*)&As[ib * 2048 + rr * 32 + cc + 4] = u;
  };

  f32x4 acc[2][2];
#pragma unroll
  for (int i = 0; i < 2; ++i)
#pragma unroll
    for (int j = 0; j < 2; ++j)
#pragma unroll
      for (int r = 0; r < 4; ++r) acc[i][j][r] = 0.0f;

  stageB(0, 0);
  if (AF32) {
    float4 a0 = *(const float4*)&Af[(long)(m0 + rr) * K + cc];
    float4 a1 = *(const float4*)&Af[(long)(m0 + rr) * K + cc + 4];
    writeAf32(0, a0, a1);
  } else {
    stageAbf(0, 0);
  }

  int ib = 0;
  for (int k0 = 0; k0 < K; k0 += 32, ib ^= 1) {
    __syncthreads();
    const int kn = k0 + 32;
    float4 a0, a1;
    if (kn < K) {
      stageB(ib ^ 1, kn);
      if (AF32) {
        a0 = *(const float4*)&Af[(long)(m0 + rr) * K + kn + cc];
        a1 = *(const float4*)&Af[(long)(m0 + rr) * K + kn + cc + 4];
      } else {
        stageAbf(ib ^ 1, kn);
      }
    }
    bf16x8 fa[2], fb[2];
#pragma unroll
    for (int i = 0; i < 2; ++i) fa[i] = *(const bf16x8*)&As[ib * 2048 + (wm + i * 16 + ln16) * 32 + quad * 8];
#pragma unroll
    for (int j = 0; j < 2; ++j) fb[j] = *(const bf16x8*)&Bs[ib * 2048 + (wn + j * 16 + ln16) * 32 + quad * 8];
#pragma unroll
    for (int i = 0; i < 2; ++i)
#pragma unroll
      for (int j = 0; j < 2; ++j)
        acc[i][j] = __builtin_amdgcn_mfma_f32_16x16x32_bf16(fa[i], fb[j], acc[i][j], 0, 0, 0);
    if (AF32 && kn < K) writeAf32(ib ^ 1, a0, a1);
  }

#pragma unroll
  for (int i = 0; i < 2; ++i) {
    const int row0 = m0 + wm + i * 16 + quad * 4;
#pragma unroll
    for (int j = 0; j < 2; ++j) {
      const int col = n0 + wn + j * 16 + ln16;
      if (EPI == 0 || EPI == 1) {
        float* C = (float*)C0v;
        float bv = (EPI == 1) ? bias[col] : 0.0f;
#pragma unroll
        for (int r = 0; r < 4; ++r) C[(long)(row0 + r) * N + col] = acc[i][j][r] + bv;
      } else if (EPI == 4) {
        if (n0 < 256) {
          float* kvl = (float*)C0v;
#pragma unroll
          for (int r = 0; r < 4; ++r) kvl[(long)(row0 + r) * 256 + col] = acc[i][j][r];
        } else if (wn == 0) {               // kr cols 256..287
          unsigned short* kr = (unsigned short*)C1v;
          const int d = col - 256;          // 0..31
#pragma unroll
          for (int r = 0; r < 4; ++r) {
            const float v = acc[i][j][r];
            const float p = __shfl_xor(v, 1);
            const float2 t = cst[((row0 + r) & (SEQ - 1)) * 16 + (d >> 1)];
            const float o = ((d & 1) == 0) ? (v * t.x - p * t.y) : (p * t.y + v * t.x);
            kr[(long)(row0 + r) * 32 + d] = f2bf(o * 0.0625f);
          }
        }
      }
    }
  }
}

template <int EPI, bool AF32>
__global__ __launch_bounds__(256) void gemm_mfma64(
    const void* __restrict__ Av, const unsigned short* __restrict__ BT,
    const float* __restrict__ bias, const float2* __restrict__ cst,
    void* __restrict__ C0v, void* __restrict__ C1v, int K, int N)
{
  __shared__ unsigned short smem[8192];
  gemm_body64<EPI, AF32>(smem, Av, BT, bias, cst, C0v, C1v, K, N, blockIdx.x, blockIdx.y);
}

template <int E0, bool AF0, int E1, bool AF1>
__global__ __launch_bounds__(256) void gemm_dual64(
    const void* __restrict__ A0, const unsigned short* __restrict__ BT0,
    void* __restrict__ C00, void* __restrict__ C01, int K0, int N0, int nx0,
    const void* __restrict__ A1, const unsigned short* __restrict__ BT1,
    void* __restrict__ C10, void* __restrict__ C11, int K1, int N1,
    const float2* __restrict__ cst)
{
  __shared__ unsigned short smem[8192];
  if (blockIdx.z == 0) {
    if ((int)blockIdx.x >= nx0) return;
    gemm_body64<E0, AF0>(smem, A0, BT0, nullptr, cst, C00, C01, K0, N0, blockIdx.x, blockIdx.y);
  } else {
    gemm_body64<E1, AF1>(smem, A1, BT1, nullptr, cst, C10, C11, K1, N1, blockIdx.x, blockIdx.y);
  }
}

// ============ 64x128-tile bf16 GEMM (deep-K, f32+bias out) — for out = o @ Wo ======
__global__ __launch_bounds__(256) void gemm_wide_kernel(
    const unsigned short* __restrict__ A, const unsigned short* __restrict__ BT,
    const float* __restrict__ bias, float* __restrict__ C, int K, int N)
{
  __shared__ unsigned short smem[12288];   // As 2x64x32 (4096) | Bs 2x128x32 (8192)
  unsigned short* As = smem;
  unsigned short* Bs = smem + 4096;
  const int tid = threadIdx.x;
  const int w = tid >> 6, lane = tid & 63;
  const int ln16 = lane & 15, quad = lane >> 4;
  const int wm = (w >> 1) * 32, wn = (w & 1) * 64;
  const int m0 = blockIdx.y * 64, n0 = blockIdx.x * 128;
  const int rr = tid >> 2, cc = (tid & 3) * 8;

  auto stageA = [&](int ib, int k0) {
    gload16(&A[(long)(m0 + rr) * K + k0 + cc], &As[ib * 2048 + rr * 32 + cc]);
  };
  auto stageB = [&](int ib, int k0) {
    gload16(&BT[(long)(n0 + rr)      * K + k0 + cc], &Bs[ib * 4096 + rr * 32 + cc]);
    gload16(&BT[(long)(n0 + 64 + rr) * K + k0 + cc], &Bs[ib * 4096 + (64 + rr) * 32 + cc]);
  };

  f32x4 acc[2][4];
#pragma unroll
  for (int i = 0; i < 2; ++i)
#pragma unroll
    for (int j = 0; j < 4; ++j)
#pragma unroll
      for (int r = 0; r < 4; ++r) acc[i][j][r] = 0.0f;

  stageA(0, 0);
  stageB(0, 0);

  int ib = 0;
  for (int k0 = 0; k0 < K; k0 += 32, ib ^= 1) {
    __syncthreads();
    const int kn = k0 + 32;
    if (kn < K) { stageA(ib ^ 1, kn); stageB(ib ^ 1, kn); }
    bf16x8 fa[2], fb[4];
#pragma unroll
    for (int i = 0; i < 2; ++i) fa[i] = *(const bf16x8*)&As[ib * 2048 + (wm + i * 16 + ln16) * 32 + quad * 8];
#pragma unroll
    for (int j = 0; j < 4; ++j) fb[j] = *(const bf16x8*)&Bs[ib * 4096 + (wn + j * 16 + ln16) * 32 + quad * 8];
#pragma unroll
    for (int i = 0; i < 2; ++i)
#pragma unroll
      for (int j = 0; j < 4; ++j)
        acc[i][j] = __builtin_amdgcn_mfma_f32_16x16x32_bf16(fa[i], fb[j], acc[i][j], 0, 0, 0);
  }

#pragma unroll
  for (int i = 0; i < 2; ++i) {
    const int row0 = m0 + wm + i * 16 + quad * 4;
#pragma unroll
    for (int j = 0; j < 4; ++j) {
      const int col = n0 + wn + j * 16 + ln16;
      const float bv = bias[col];
#pragma unroll
      for (int r = 0; r < 4; ++r) C[(long)(row0 + r) * N + col] = acc[i][j][r] + bv;
    }
  }
}

// ------------- merged LayerNorm: rows 0..4095 -> ql, 4096..8191 -> kvl -------
__global__ __launch_bounds__(256) void ln2_kernel(
    const float* __restrict__ Xq, const float* __restrict__ Xkv,
    const float* __restrict__ gq, const float* __restrict__ bq,
    const float* __restrict__ gkv, const float* __restrict__ bkv,
    unsigned short* __restrict__ Yq, unsigned short* __restrict__ Ykv)
{
  const int row0 = blockIdx.x, tid = threadIdx.x;
  const bool isq = row0 < 4096;
  const int row = isq ? row0 : row0 - 4096;
  const float* X = isq ? Xq : Xkv;
  const float* g = isq ? gq : gkv;
  const float* b = isq ? bq : bkv;
  unsigned short* Y = isq ? Yq : Ykv;
  const int C = isq ? 256 : 204;
  const int Cp = isq ? 256 : 224;
  float v = (tid < C) ? X[(long)row * 256 + tid] : 0.0f;
  float s1 = v, s2 = v * v;
#pragma unroll
  for (int off = 1; off < 64; off <<= 1) {
    s1 += __shfl_xor(s1, off);
    s2 += __shfl_xor(s2, off);
  }
  __shared__ float rA[4], rB[4];
  const int wid = tid >> 6;
  if ((tid & 63) == 0) { rA[wid] = s1; rB[wid] = s2; }
  __syncthreads();
  s1 = rA[0] + rA[1] + rA[2] + rA[3];
  s2 = rB[0] + rB[1] + rB[2] + rB[3];
  const float mean = s1 / C;
  const float var  = s2 / C - mean * mean;
  const float r = rsqrtf(var + 1e-5f);
  if (tid < C) Y[(long)row * Cp + tid] = f2bf((v - mean) * r * g[tid] + b[tid]);
  else if (tid < Cp) Y[(long)row * Cp + tid] = 0;
}

// ---------------- MFMA flash attention: SPLIT-S, t-tile 128, XCD-swizzled -----------
// grid = 1024 (= 4 blocks/CU), block 256. Each block handles HALF the s-range (1024)
// for one (bh, t-tile): no-max softmax partials combine exactly linearly -> partial
// o (f32) + l to workspace, combined by attn_combine_kernel. Barriers are lgkm-only
// (ds-write drain); global prefetches stay in flight across them (T4 principle).
// P stays in registers via cvt_pk + permlane32/16_swap.
#define KSTR 36
#define VSTR 68
__global__ __launch_bounds__(256, 4) void attn_mfma_kernel(
    const unsigned short* __restrict__ qn, const unsigned short* __restrict__ qr,
    const unsigned short* __restrict__ kn, const unsigned short* __restrict__ kr,
    const unsigned short* __restrict__ vT, float* __restrict__ po,
    float* __restrict__ pl)
{
  __shared__ unsigned short Kn[2][64 * KSTR];
  __shared__ unsigned short Vs[2][64 * VSTR];   // Vs[d][s]
  const int id = blockIdx.x;
  const int xcd = id & 7, j = id >> 3;          // j in 0..127
  const int bh = xcd * 4 + (j & 3);             // all work of bh on one XCD
  const int rest = j >> 2;                      // 0..31
  const int tile = rest >> 1;                   // 0..15
  const int hp = rest & 1;                      // s-half 0/1
  const int b = bh >> 4, h = bh & 15;
  const int t0 = tile * 128;
  const int sBase = hp * 1024, sEnd = sBase + 1024;
  const int tid = threadIdx.x;
  const int w = tid >> 6, lane = tid & 63;
  const int ln16 = lane & 15, quad = lane >> 4;
  const int trow = w * 16;
  const long bT = (long)b * SEQ;

  // staging indices
  const int krow = tid >> 2, kc8 = (tid & 3) * 8;          // Kn: 64 rows x 32
  const int vd0 = tid >> 3, vc0 = (tid & 7) * 8;           // V: segs tid, tid+256
  const int vd1 = vd0 + 32;

  // Q fragments in registers: group A = rows t0+trow, group B = rows t0+64+trow
  bf16x8 q0A = *(const bf16x8*)&qn[(bT + t0 + trow + ln16) * 512 + h * 32 + quad * 8];
  bf16x8 q1A = *(const bf16x8*)&qr[(bT + t0 + trow + ln16) * 512 + h * 32 + quad * 8];
  bf16x8 q0B = *(const bf16x8*)&qn[(bT + t0 + 64 + trow + ln16) * 512 + h * 32 + quad * 8];
  bf16x8 q1B = *(const bf16x8*)&qr[(bT + t0 + 64 + trow + ln16) * 512 + h * 32 + quad * 8];

  auto loadKV = [&](int s0, bf16x8& rk0, bf16x8& rv0, bf16x8& rv1) {
    rk0 = *(const bf16x8*)&kn[(bT + s0 + krow) * 512 + h * 32 + kc8];
    rv0 = *(const bf16x8*)&vT[((long)bh * 64 + vd0) * SEQ + s0 + vc0];
    rv1 = *(const bf16x8*)&vT[((long)bh * 64 + vd1) * SEQ + s0 + vc0];
  };
  auto writeKV = [&](int ib, bf16x8 rk0, bf16x8 rv0, bf16x8 rv1) {
    *(bf16x8*)&Kn[ib][krow * KSTR + kc8] = rk0;
    *(bf16x8*)&Vs[ib][vd0 * VSTR + vc0] = rv0;
    *(bf16x8*)&Vs[ib][vd1 * VSTR + vc0] = rv1;
  };
  // kr A-fragments straight from global (L2-hot: shared by all h of this b)
  auto loadKrF = [&](int s0, bf16x8* f) {
#pragma unroll
    for (int nt = 0; nt < 4; ++nt)
      f[nt] = *(const bf16x8*)&kr[(bT + s0 + nt * 16 + ln16) * 32 + quad * 8];
  };
  // P transform: sf (4x f32x4, swapped-QK layout) -> two bf16x8 PV A-fragments
  auto pxform = [&](const f32x4* sf, float& l_part, bf16x8& a0, bf16x8& a1) {
    float p[16];
#pragma unroll
    for (int nt = 0; nt < 4; ++nt)
#pragma unroll
      for (int r = 0; r < 4; ++r) {
        const float e = EXP2(sf[nt][r]);
        p[nt * 4 + r] = e;
        l_part += e;
      }
    unsigned u0 = cvtpk(p[0],  p[1]),  u1 = cvtpk(p[2],  p[3]);
    unsigned u2 = cvtpk(p[4],  p[5]),  u3 = cvtpk(p[6],  p[7]);
    unsigned u4 = cvtpk(p[8],  p[9]),  u5 = cvtpk(p[10], p[11]);
    unsigned u6 = cvtpk(p[12], p[13]), u7 = cvtpk(p[14], p[15]);
    plswap32(u0, u2); plswap16(u0, u2);
    plswap32(u1, u3); plswap16(u1, u3);
    plswap32(u4, u6); plswap16(u4, u6);
    plswap32(u5, u7); plswap16(u5, u7);
    const uint4 w0 = make_uint4(u0, u1, u2, u3);   // P[t=ln16][s = 8q .. 8q+7]
    const uint4 w1 = make_uint4(u4, u5, u6, u7);   // P[t=ln16][s = 32+8q .. +7]
    a0 = __builtin_bit_cast(bf16x8, w0);
    a1 = __builtin_bit_cast(bf16x8, w1);
  };

  bf16x8 ck0, cv0, cv1;
  bf16x8 nk0, nv0, nv1;
  bf16x8 ckr[4];
  loadKV(sBase, ck0, cv0, cv1);
  writeKV(0, ck0, cv0, cv1);
  loadKV(sBase + 64, nk0, nv0, nv1);
  loadKrF(sBase, ckr);

  f32x4 o_acc[2][4];
#pragma unroll
  for (int g = 0; g < 2; ++g)
#pragma unroll
    for (int nt = 0; nt < 4; ++nt)
#pragma unroll
      for (int r = 0; r < 4; ++r) o_acc[g][nt][r] = 0.0f;
  float l_part[2] = {0.0f, 0.0f};      // per-lane partials, groups A/B

  int ib = 0;
  for (int s0 = sBase; s0 < sEnd; s0 += 64, ib ^= 1) {
    // lgkm-only barrier: ds-writes drained, global prefetches stay in flight
    asm volatile("s_waitcnt lgkmcnt(0)\n\ts_barrier" ::: "memory");
    if (s0 + 64 < sEnd) {
      writeKV(ib ^ 1, nk0, nv0, nv1);
      if (s0 + 128 < sEnd) loadKV(s0 + 128, nk0, nv0, nv1);
    }

    // K fragments: read ONCE, feed both t-groups
    bf16x8 ka[4];
#pragma unroll
    for (int nt = 0; nt < 4; ++nt)
      ka[nt] = *(const bf16x8*)&Kn[ib][(nt * 16 + ln16) * KSTR + quad * 8];

    // S^T = K @ Q^T for both groups
    f32x4 sfA[4], sfB[4];
#pragma unroll
    for (int nt = 0; nt < 4; ++nt)
#pragma unroll
      for (int r = 0; r < 4; ++r) { sfA[nt][r] = 0.0f; sfB[nt][r] = 0.0f; }
#pragma unroll
    for (int nt = 0; nt < 4; ++nt) {
      sfA[nt] = __builtin_amdgcn_mfma_f32_16x16x32_bf16(ka[nt], q0A, sfA[nt], 0, 0, 0);
      sfA[nt] = __builtin_amdgcn_mfma_f32_16x16x32_bf16(ckr[nt], q1A, sfA[nt], 0, 0, 0);
    }
#pragma unroll
    for (int nt = 0; nt < 4; ++nt) {
      sfB[nt] = __builtin_amdgcn_mfma_f32_16x16x32_bf16(ka[nt], q0B, sfB[nt], 0, 0, 0);
      sfB[nt] = __builtin_amdgcn_mfma_f32_16x16x32_bf16(ckr[nt], q1B, sfB[nt], 0, 0, 0);
    }

    // ckr consumed: reload for next s-tile (L2-hot; latency hidden by softmax+PV)
    if (s0 + 64 < sEnd) loadKrF(s0 + 64, ckr);

    bf16x8 a0A, a1A, a0B, a1B;
    pxform(sfA, l_part[0], a0A, a1A);
    pxform(sfB, l_part[1], a0B, a1B);

    // O += P(16 x 64) @ V(64 x 64), V fragments read ONCE for both groups
#pragma unroll
    for (int nt = 0; nt < 4; ++nt) {
      bf16x8 v0 = *(const bf16x8*)&Vs[ib][(nt * 16 + ln16) * VSTR + quad * 8];
      o_acc[0][nt] = __builtin_amdgcn_mfma_f32_16x16x32_bf16(a0A, v0, o_acc[0][nt], 0, 0, 0);
      o_acc[1][nt] = __builtin_amdgcn_mfma_f32_16x16x32_bf16(a0B, v0, o_acc[1][nt], 0, 0, 0);
      bf16x8 v1 = *(const bf16x8*)&Vs[ib][(nt * 16 + ln16) * VSTR + 32 + quad * 8];
      o_acc[0][nt] = __builtin_amdgcn_mfma_f32_16x16x32_bf16(a1A, v1, o_acc[0][nt], 0, 0, 0);
      o_acc[1][nt] = __builtin_amdgcn_mfma_f32_16x16x32_bf16(a1B, v1, o_acc[1][nt], 0, 0, 0);
    }
  }

  // per-group cross-quad l reduction + partial writes (NOT normalized)
  const long poB = (long)hp * 4096 * 1024;
#pragma unroll
  for (int g = 0; g < 2; ++g) {
    float l_i = l_part[g];
    l_i += __shfl_xor(l_i, 16);
    l_i += __shfl_xor(l_i, 32);
    if (quad == 0) {
      const int tl = t0 + g * 64 + trow + ln16;
      pl[hp * 65536 + bh * 2048 + tl] = l_i;
    }
#pragma unroll
    for (int r = 0; r < 4; ++r) {
      const long t = t0 + g * 64 + trow + quad * 4 + r;
      const long base = poB + (bT + t) * 1024 + h * 64 + ln16;
#pragma unroll
      for (int nt = 0; nt < 4; ++nt)
        po[base + nt * 16] = o_acc[g][nt][r];
    }
  }
}

// combine: o_bf[t][h*64+d] = (po0 + po1) / (l0 + l1), 2 rows per block
__global__ __launch_bounds__(256) void attn_combine_kernel(
    const float* __restrict__ po, const float* __restrict__ pl,
    unsigned short* __restrict__ ob)
{
  const int row = blockIdx.x * 2 + (threadIdx.x >> 7);       // 0..4095
  const int col = (threadIdx.x & 127) * 8;                   // 0..1016, h-aligned
  const int b = row >> 11, t = row & 2047;
  const int h = col >> 6;
  const int bh = b * 16 + h;
  const float l0 = pl[bh * 2048 + t];
  const float l1 = pl[65536 + bh * 2048 + t];
  const float lr = 1.0f / (l0 + l1);
  const long base = (long)row * 1024 + col;
  const float4 a0 = *(const float4*)&po[base];
  const float4 a1 = *(const float4*)&po[base + 4];
  const float4 b0 = *(const float4*)&po[4194304L + base];
  const float4 b1 = *(const float4*)&po[4194304L + base + 4];
  ushort4 u0, u1;
  u0.x = f2bf((a0.x + b0.x) * lr); u0.y = f2bf((a0.y + b0.y) * lr);
  u0.z = f2bf((a0.z + b0.z) * lr); u0.w = f2bf((a0.w + b0.w) * lr);
  u1.x = f2bf((a1.x + b1.x) * lr); u1.y = f2bf((a1.y + b1.y) * lr);
  u1.z = f2bf((a1.z + b1.z) * lr); u1.w = f2bf((a1.w + b1.w) * lr);
  *(ushort4*)&ob[base] = u0;
  *(ushort4*)&ob[base + 4] = u1;
}

extern "C" void kernel_launch(void* const* d_in, const int* in_sizes, int n_in,
                              void* d_out, int out_size, void* d_ws, size_t ws_size,
                              hipStream_t stream) {
  const float* x       = (const float*)d_in[0];
  const float* xf      = (const float*)d_in[1];
  const float* Wqc     = (const float*)d_in[2];
  const float* gq      = (const float*)d_in[3];
  const float* bq      = (const float*)d_in[4];
  const float* Wq_rope = (const float*)d_in[5];   // rope before nope in dict order
  const float* Wq_nope = (const float*)d_in[6];
  const float* Wkvc    = (const float*)d_in[7];
  const float* gkv     = (const float*)d_in[8];
  const float* bkv     = (const float*)d_in[9];
  const float* Wk_nope = (const float*)d_in[10];
  const float* Wv      = (const float*)d_in[11];
  const float* Wkr     = (const float*)d_in[12];
  const float* Wo      = (const float*)d_in[13];
  const float* bo      = (const float*)d_in[14];
  float* out = (float*)d_out;

  const long R = 4096;
  float* ws = (float*)d_ws;
  float* ql_f  = ws;                       // 4096 x 256 f32
  float* kvl_f = ql_f + R * 256;           // 4096 x 256 f32
  float2* cst  = (float2*)(kvl_f + R * 256);  // 2048 x 16 cos/sin pairs
  unsigned short* us = (unsigned short*)(cst + 2048 * 16);
  unsigned short* ql_bf  = us;  us += R * 256;
  unsigned short* kvl_bf = us;  us += R * 224;    // K-padded to 224
  unsigned short* qn_bf  = us;  us += R * 512;
  unsigned short* qr_bf  = us;  us += R * 512;
  unsigned short* kn_bf  = us;  us += R * 512;
  unsigned short* kr_bf  = us;  us += R * 32;
  unsigned short* vT_bf  = us;  us += R * 1024;   // (B,H,64,S)
  unsigned short* o_bf   = us;  us += R * 1024;
  unsigned short* WqcT   = us;  us += 256 * 1024;
  unsigned short* WkvkrT = us;  us += 384 * 1024; // [Wkvc^T pad256 | Wkr^T pad128]
  unsigned short* WqnqrT = us;  us += 1024 * 256; // [Wq_nope^T | Wq_rope^T]
  unsigned short* WknvT  = us;  us += 1536 * 224; // [Wk_nope^T | Wv^T], K pad 224
  unsigned short* WoT    = us;  us += 1024 * 1024;
  float* po = (float*)us;                  // 2 x 4096 x 1024 f32 partial O
  float* pl = po + 2L * 4096 * 1024;       // 2 x 32 x 2048 f32 partial l

  // 0) mega prep: rope table + 8 weight transposes in one dispatch
  WPrep p;
  const float* srcs[8] = {Wqc, Wkvc, Wkr, Wq_nope, Wq_rope, Wk_nope, Wv, Wo};
  unsigned short* dsts[8] = {WqcT, WkvkrT, WkvkrT + 256 * 1024,
                             WqnqrT, WqnqrT + 512 * 256,
                             WknvT, WknvT + 512 * 224, WoT};
  const int Ks[8]  = {1024, 1024, 1024, 256, 256, 204, 204, 1024};
  const int Ns[8]  = {256, 204, 32, 512, 512, 512, 1024, 1024};
  const int NRs[8] = {256, 256, 128, 512, 512, 512, 1024, 1024};
  const int KCs[8] = {1024, 1024, 1024, 256, 256, 224, 224, 1024};
  int total = 128;
  for (int i = 0; i < 8; ++i) {
    p.src[i] = srcs[i]; p.dst[i] = dsts[i];
    p.K[i] = Ks[i]; p.N[i] = Ns[i]; p.NR[i] = NRs[i]; p.KC[i] = KCs[i];
    p.nb[i] = (KCs[i] / 32) * (NRs[i] / 32);
    total += p.nb[i];
  }
  p.cst = cst;
  wprep_kernel<<<total, 256, 0, stream>>>(p);

  // 1) dual 64-tile GEMM (deep K=1024, 768 blocks): z=0 ql_f = x @ Wqc ;
  //    z=1 [kvl | kr] = xf @ [Wkvc | Wkr] (+rope/16)
  gemm_dual64<0, true, 4, true><<<dim3(6, 64, 2), 256, 0, stream>>>(
      x, WqcT, ql_f, nullptr, 1024, 256, 4,
      xf, WkvkrT, kvl_f, kr_bf, 1024, 384, cst);
  // 2) merged LN
  ln2_kernel<<<8192, 256, 0, stream>>>(ql_f, kvl_f, gq, bq, gkv, bkv, ql_bf, kvl_bf);
  // 3) dual 128-tile GEMM (short K, wide N): z=0 [qn|qr] (+rope, *CLOG) ; z=1 [kn|vT]
  gemm_dual<3, false, 5, false><<<dim3(12, 32, 2), 256, 0, stream>>>(
      ql_bf, WqnqrT, qn_bf, qr_bf, 256, 1024, 8,
      kvl_bf, WknvT, kn_bf, vT_bf, 224, 1536, cst);
  // 4) attention partials (split-s, 4 blocks/CU) + exact linear combine
  attn_mfma_kernel<<<1024, 256, 0, stream>>>(qn_bf, qr_bf, kn_bf, kr_bf, vT_bf, po, pl);
  attn_combine_kernel<<<2048, 256, 0, stream>>>(po, pl, o_bf);
  // 5) out = o @ Wo + bo (fp32), 64x128-tile deep-K: 512 blocks = 2/CU
  gemm_wide_kernel<<<dim3(8, 64), 256, 0, stream>>>(o_bf, WoT, bo, out, 1024, 1024);
}

// Round 8
// 211.542 us; speedup vs baseline: 1.2919x; 1.2919x over previous
//
#include <hip/hip_runtime.h>
#include <hip/hip_bf16.h>
#include <math.h>

#define SEQ 2048

typedef __bf16 bf16x8 __attribute__((ext_vector_type(8)));
typedef float  f32x4  __attribute__((ext_vector_type(4)));

#if __has_builtin(__builtin_amdgcn_exp2f)
#define EXP2(x) __builtin_amdgcn_exp2f(x)
#else
#define EXP2(x) exp2f(x)
#endif

__device__ __forceinline__ unsigned short f2bf(float f) {
  __bf16 h = (__bf16)f;
  return __builtin_bit_cast(unsigned short, h);
}

__device__ __forceinline__ void gload16(const unsigned short* g, unsigned short* l) {
  __builtin_amdgcn_global_load_lds(
      (const __attribute__((address_space(1))) void*)g,
      (__attribute__((address_space(3))) void*)l, 16, 0, 0);
}

// packed f32->bf16 convert (RNE, same rounding as scalar (__bf16) cast)
__device__ __forceinline__ unsigned cvtpk(float lo, float hi) {
  unsigned r;
  asm("v_cvt_pk_bf16_f32 %0, %1, %2" : "=v"(r) : "v"(lo), "v"(hi));
  return r;
}
// a[32:63] <-> b[0:31]:  a' = [a_q0,a_q1,b_q0,b_q1], b' = [a_q2,a_q3,b_q2,b_q3]
__device__ __forceinline__ void plswap32(unsigned &a, unsigned &b) {
  asm("v_permlane32_swap_b32 %0, %1" : "+v"(a), "+v"(b));
}
// odd 16-rows of a <-> even 16-rows of b: a' = [a0,b0,a2,b2], b' = [a1,b1,a3,b3]
__device__ __forceinline__ void plswap16(unsigned &a, unsigned &b) {
  asm("v_permlane16_swap_b32 %0, %1" : "+v"(a), "+v"(b));
}

#define CLOG (0.125f * 1.44269504f)   // 1/sqrt(HD) * log2(e), folded into q

// ===== mega prep: rope table + x/xf f32->bf16 convert + 8 weight transposes =====
struct WPrep {
  const float* src[8];
  unsigned short* dst[8];
  int K[8], N[8], NR[8], KC[8], nb[8];
  float2* cst;
  const float* xs[2];
  unsigned short* xd[2];
};

__global__ __launch_bounds__(256) void wprep_kernel(WPrep p)
{
  __shared__ float tile[32][33];
  int bid = blockIdx.x;
  if (bid < 128) {                       // rope table: 32768 entries
    const int idx = bid * 256 + threadIdx.x;
    const int pos = idx >> 4, i = idx & 15;
    const float freq = EXP2(-(float)i * 0.8304820237f);
    const float ang = (float)pos * freq;
    p.cst[idx] = make_float2(cosf(ang), sinf(ang));
    return;
  }
  bid -= 128;
  if (bid < 4096) {                      // x/xf f32 -> bf16 (2048 blocks each)
    const int sel = bid >> 11;
    const long base = (long)(bid & 2047) * 2048 + threadIdx.x * 8;
    const float4 a = *(const float4*)&p.xs[sel][base];
    const float4 b = *(const float4*)&p.xs[sel][base + 4];
    ushort4 u0, u1;
    u0.x = f2bf(a.x); u0.y = f2bf(a.y); u0.z = f2bf(a.z); u0.w = f2bf(a.w);
    u1.x = f2bf(b.x); u1.y = f2bf(b.y); u1.z = f2bf(b.z); u1.w = f2bf(b.w);
    *(ushort4*)&p.xd[sel][base] = u0;
    *(ushort4*)&p.xd[sel][base + 4] = u1;
    return;
  }
  bid -= 4096;
  int di = 0;
  while (bid >= p.nb[di]) { bid -= p.nb[di]; ++di; }
  const float* src = p.src[di];
  unsigned short* dst = p.dst[di];
  const int K = p.K[di], N = p.N[di], KC = p.KC[di];
  const int nkx = KC >> 5;
  const int k0 = (bid % nkx) * 32, n0 = (bid / nkx) * 32;
  const int tx = threadIdx.x & 31, ty = threadIdx.x >> 5;
  for (int r = ty; r < 32; r += 8) {
    const int k = k0 + r, n = n0 + tx;
    tile[r][tx] = (k < K && n < N) ? src[(long)k * N + n] : 0.0f;
  }
  __syncthreads();
  for (int r = ty; r < 32; r += 8) {
    const int n = n0 + r, k = k0 + tx;
    dst[(long)n * KC + k] = f2bf(tile[tx][r]);
  }
}

// ============ 128-tile bf16 MFMA GEMM body (for wide-N, short-K GEMMs) ============
// EPI: 3 QROPE: cols<512 -> qn (*CLOG); cols>=512 rope -> qr (*CLOG)   [stride 512]
//      5 KNV:   cols<512 -> kn (stride 512); cols>=512 -> vT (B,H,64,S) via LDS transpose
template <int EPI, bool AF32>
__device__ __forceinline__ void gemm_body(
    unsigned short* smem,                     // 16896 shorts
    const void* __restrict__ Av, const unsigned short* __restrict__ BT,
    const float* __restrict__ bias, const float2* __restrict__ cst,
    void* __restrict__ C0v, void* __restrict__ C1v, int K, int N,
    int bx, int by)
{
  unsigned short* As = smem;               // [2][128*32]
  unsigned short* Bs = smem + 2 * 128 * 32;
  const int tid = threadIdx.x;
  const int w = tid >> 6, lane = tid & 63;
  const int ln16 = lane & 15, quad = lane >> 4;
  const int wm = (w >> 1) * 64, wn = (w & 1) * 64;
  const int m0 = by * 128, n0 = bx * 128;
  const int rr = tid >> 2, cc = (tid & 3) * 8;

  const unsigned short* A = (const unsigned short*)Av;

  auto stageB = [&](int ib, int k0) {
    gload16(&BT[(long)(n0 + rr)      * K + k0 + cc], &Bs[ib * 4096 + rr * 32 + cc]);
    gload16(&BT[(long)(n0 + 64 + rr) * K + k0 + cc], &Bs[ib * 4096 + (64 + rr) * 32 + cc]);
  };
  auto stageAbf = [&](int ib, int k0) {
    gload16(&A[(long)(m0 + rr)      * K + k0 + cc], &As[ib * 4096 + rr * 32 + cc]);
    gload16(&A[(long)(m0 + 64 + rr) * K + k0 + cc], &As[ib * 4096 + (64 + rr) * 32 + cc]);
  };

  f32x4 acc[4][4];
#pragma unroll
  for (int i = 0; i < 4; ++i)
#pragma unroll
    for (int j = 0; j < 4; ++j)
#pragma unroll
      for (int r = 0; r < 4; ++r) acc[i][j][r] = 0.0f;

  stageB(0, 0);
  stageAbf(0, 0);

  int ib = 0;
  for (int k0 = 0; k0 < K; k0 += 32, ib ^= 1) {
    __syncthreads();
    const int kn = k0 + 32;
    if (kn < K) { stageB(ib ^ 1, kn); stageAbf(ib ^ 1, kn); }
    bf16x8 fa[4], fb[4];
#pragma unroll
    for (int i = 0; i < 4; ++i) fa[i] = *(const bf16x8*)&As[ib * 4096 + (wm + i * 16 + ln16) * 32 + quad * 8];
#pragma unroll
    for (int j = 0; j < 4; ++j) fb[j] = *(const bf16x8*)&Bs[ib * 4096 + (wn + j * 16 + ln16) * 32 + quad * 8];
#pragma unroll
    for (int i = 0; i < 4; ++i)
#pragma unroll
      for (int j = 0; j < 4; ++j)
        acc[i][j] = __builtin_amdgcn_mfma_f32_16x16x32_bf16(fa[i], fb[j], acc[i][j], 0, 0, 0);
  }

  // ----- epilogues -----
  if (EPI == 5 && n0 >= 512) {
    // fused V transpose: acc tile (128 s-rows x 128 cols) -> vT (B,H,64,S) coalesced
    __syncthreads();
#pragma unroll
    for (int i = 0; i < 4; ++i) {
      const int rl = wm + i * 16 + quad * 4;
#pragma unroll
      for (int j = 0; j < 4; ++j) {
        const int cl = wn + j * 16 + ln16;
        ushort4 u;
        u.x = f2bf(acc[i][j][0]); u.y = f2bf(acc[i][j][1]);
        u.z = f2bf(acc[i][j][2]); u.w = f2bf(acc[i][j][3]);
        *(ushort4*)&smem[cl * 132 + rl] = u;
      }
    }
    __syncthreads();
    unsigned short* vT = (unsigned short*)C1v;
    const int b = m0 >> 11, sbase = m0 & (SEQ - 1);
    for (int q = tid; q < 128 * 16; q += 256) {
      const int cl = q >> 4, sch = (q & 15) * 8;
      bf16x8 val = *(const bf16x8*)&smem[cl * 132 + sch];
      const int c = (n0 - 512) + cl;
      const int hh = c >> 6, dd = c & 63;
      *(bf16x8*)&vT[((long)(b * 16 + hh) * 64 + dd) * SEQ + sbase + sch] = val;
    }
    return;
  }
#pragma unroll
  for (int i = 0; i < 4; ++i) {
    const int row0 = m0 + wm + i * 16 + quad * 4;
#pragma unroll
    for (int j = 0; j < 4; ++j) {
      const int col = n0 + wn + j * 16 + ln16;
      if (EPI == 3) {
        if (n0 < 512) {
          unsigned short* qn = (unsigned short*)C0v;
#pragma unroll
          for (int r = 0; r < 4; ++r) qn[(long)(row0 + r) * 512 + col] = f2bf(acc[i][j][r] * CLOG);
        } else {
          unsigned short* qr = (unsigned short*)C1v;
          const int c = col - 512;
          const int d = c & 31;
#pragma unroll
          for (int r = 0; r < 4; ++r) {
            const float v = acc[i][j][r];
            const float p = __shfl_xor(v, 1);
            const float2 t = cst[((row0 + r) & (SEQ - 1)) * 16 + (d >> 1)];
            const float o = ((d & 1) == 0) ? (v * t.x - p * t.y) : (p * t.y + v * t.x);
            qr[(long)(row0 + r) * 512 + c] = f2bf(o * CLOG);
          }
        }
      } else if (EPI == 5) {
        unsigned short* kn = (unsigned short*)C0v;
#pragma unroll
        for (int r = 0; r < 4; ++r) kn[(long)(row0 + r) * 512 + col] = f2bf(acc[i][j][r]);
      }
    }
  }
}

// dual 128-tile wrapper
template <int E0, bool AF0, int E1, bool AF1>
__global__ __launch_bounds__(256) void gemm_dual(
    const void* __restrict__ A0, const unsigned short* __restrict__ BT0,
    void* __restrict__ C00, void* __restrict__ C01, int K0, int N0, int nx0,
    const void* __restrict__ A1, const unsigned short* __restrict__ BT1,
    void* __restrict__ C10, void* __restrict__ C11, int K1, int N1,
    const float2* __restrict__ cst)
{
  __shared__ unsigned short smem[16896];
  if (blockIdx.z == 0) {
    if ((int)blockIdx.x >= nx0) return;
    gemm_body<E0, AF0>(smem, A0, BT0, nullptr, cst, C00, C01, K0, N0, blockIdx.x, blockIdx.y);
  } else {
    gemm_body<E1, AF1>(smem, A1, BT1, nullptr, cst, C10, C11, K1, N1, blockIdx.x, blockIdx.y);
  }
}

// ============ 64x128-tile bf16 GEMM body (deep-K; 8 MFMA/K-step/wave) ==============
// EPI: 0 f32->C0 ; 1 f32+bias->C0 ; 4 KVKR: cols<256 f32->kvl ; cols 256..287 rope/16->kr
template <int EPI>
__device__ __forceinline__ void gemm_wbody(
    unsigned short* smem,                     // 12288 shorts
    const unsigned short* __restrict__ A, const unsigned short* __restrict__ BT,
    const float* __restrict__ bias, const float2* __restrict__ cst,
    void* __restrict__ C0v, void* __restrict__ C1v, int K, int N,
    int bx, int by)
{
  unsigned short* As = smem;               // [2][64*32]
  unsigned short* Bs = smem + 4096;        // [2][128*32]
  const int tid = threadIdx.x;
  const int w = tid >> 6, lane = tid & 63;
  const int ln16 = lane & 15, quad = lane >> 4;
  const int wm = (w >> 1) * 32, wn = (w & 1) * 64;
  const int m0 = by * 64, n0 = bx * 128;
  const int rr = tid >> 2, cc = (tid & 3) * 8;

  auto stageA = [&](int ib, int k0) {
    gload16(&A[(long)(m0 + rr) * K + k0 + cc], &As[ib * 2048 + rr * 32 + cc]);
  };
  auto stageB = [&](int ib, int k0) {
    gload16(&BT[(long)(n0 + rr)      * K + k0 + cc], &Bs[ib * 4096 + rr * 32 + cc]);
    gload16(&BT[(long)(n0 + 64 + rr) * K + k0 + cc], &Bs[ib * 4096 + (64 + rr) * 32 + cc]);
  };

  f32x4 acc[2][4];
#pragma unroll
  for (int i = 0; i < 2; ++i)
#pragma unroll
    for (int j = 0; j < 4; ++j)
#pragma unroll
      for (int r = 0; r < 4; ++r) acc[i][j][r] = 0.0f;

  stageA(0, 0);
  stageB(0, 0);

  int ib = 0;
  for (int k0 = 0; k0 < K; k0 += 32, ib ^= 1) {
    __syncthreads();
    const int kn = k0 + 32;
    if (kn < K) { stageA(ib ^ 1, kn); stageB(ib ^ 1, kn); }
    bf16x8 fa[2], fb[4];
#pragma unroll
    for (int i = 0; i < 2; ++i) fa[i] = *(const bf16x8*)&As[ib * 2048 + (wm + i * 16 + ln16) * 32 + quad * 8];
#pragma unroll
    for (int j = 0; j < 4; ++j) fb[j] = *(const bf16x8*)&Bs[ib * 4096 + (wn + j * 16 + ln16) * 32 + quad * 8];
#pragma unroll
    for (int i = 0; i < 2; ++i)
#pragma unroll
      for (int j = 0; j < 4; ++j)
        acc[i][j] = __builtin_amdgcn_mfma_f32_16x16x32_bf16(fa[i], fb[j], acc[i][j], 0, 0, 0);
  }

#pragma unroll
  for (int i = 0; i < 2; ++i) {
    const int row0 = m0 + wm + i * 16 + quad * 4;
#pragma unroll
    for (int j = 0; j < 4; ++j) {
      const int col = n0 + wn + j * 16 + ln16;
      if (EPI == 0 || EPI == 1) {
        float* C = (float*)C0v;
        const float bv = (EPI == 1) ? bias[col] : 0.0f;
#pragma unroll
        for (int r = 0; r < 4; ++r) C[(long)(row0 + r) * N + col] = acc[i][j][r] + bv;
      } else if (EPI == 4) {
        if (col < 256) {
          float* kvl = (float*)C0v;
#pragma unroll
          for (int r = 0; r < 4; ++r) kvl[(long)(row0 + r) * 256 + col] = acc[i][j][r];
        } else if (col < 288) {             // kr cols 256..287 (rope/16)
          unsigned short* kr = (unsigned short*)C1v;
          const int d = col - 256;          // 0..31
#pragma unroll
          for (int r = 0; r < 4; ++r) {
            const float v = acc[i][j][r];
            const float p = __shfl_xor(v, 1);
            const float2 t = cst[((row0 + r) & (SEQ - 1)) * 16 + (d >> 1)];
            const float o = ((d & 1) == 0) ? (v * t.x - p * t.y) : (p * t.y + v * t.x);
            kr[(long)(row0 + r) * 32 + d] = f2bf(o * 0.0625f);
          }
        }
      }
    }
  }
}

template <int EPI>
__global__ __launch_bounds__(256) void gemm_widek(
    const unsigned short* __restrict__ A, const unsigned short* __restrict__ BT,
    const float* __restrict__ bias, const float2* __restrict__ cst,
    void* __restrict__ C0, void* __restrict__ C1, int K, int N)
{
  __shared__ unsigned short smem[12288];
  gemm_wbody<EPI>(smem, A, BT, bias, cst, C0, C1, K, N, blockIdx.x, blockIdx.y);
}

template <int E0, int E1>
__global__ __launch_bounds__(256) void gemm_dualw(
    const unsigned short* __restrict__ A0, const unsigned short* __restrict__ BT0,
    void* __restrict__ C00, void* __restrict__ C01, int K0, int N0, int nx0,
    const unsigned short* __restrict__ A1, const unsigned short* __restrict__ BT1,
    void* __restrict__ C10, void* __restrict__ C11, int K1, int N1,
    const float2* __restrict__ cst)
{
  __shared__ unsigned short smem[12288];
  if (blockIdx.z == 0) {
    if ((int)blockIdx.x >= nx0) return;
    gemm_wbody<E0>(smem, A0, BT0, nullptr, cst, C00, C01, K0, N0, blockIdx.x, blockIdx.y);
  } else {
    gemm_wbody<E1>(smem, A1, BT1, nullptr, cst, C10, C11, K1, N1, blockIdx.x, blockIdx.y);
  }
}

// ------------- merged LayerNorm: rows 0..4095 -> ql, 4096..8191 -> kvl -------
__global__ __launch_bounds__(256) void ln2_kernel(
    const float* __restrict__ Xq, const float* __restrict__ Xkv,
    const float* __restrict__ gq, const float* __restrict__ bq,
    const float* __restrict__ gkv, const float* __restrict__ bkv,
    unsigned short* __restrict__ Yq, unsigned short* __restrict__ Ykv)
{
  const int row0 = blockIdx.x, tid = threadIdx.x;
  const bool isq = row0 < 4096;
  const int row = isq ? row0 : row0 - 4096;
  const float* X = isq ? Xq : Xkv;
  const float* g = isq ? gq : gkv;
  const float* b = isq ? bq : bkv;
  unsigned short* Y = isq ? Yq : Ykv;
  const int C = isq ? 256 : 204;
  const int Cp = isq ? 256 : 224;
  float v = (tid < C) ? X[(long)row * 256 + tid] : 0.0f;
  float s1 = v, s2 = v * v;
#pragma unroll
  for (int off = 1; off < 64; off <<= 1) {
    s1 += __shfl_xor(s1, off);
    s2 += __shfl_xor(s2, off);
  }
  __shared__ float rA[4], rB[4];
  const int wid = tid >> 6;
  if ((tid & 63) == 0) { rA[wid] = s1; rB[wid] = s2; }
  __syncthreads();
  s1 = rA[0] + rA[1] + rA[2] + rA[3];
  s2 = rB[0] + rB[1] + rB[2] + rB[3];
  const float mean = s1 / C;
  const float var  = s2 / C - mean * mean;
  const float r = rsqrtf(var + 1e-5f);
  if (tid < C) Y[(long)row * Cp + tid] = f2bf((v - mean) * r * g[tid] + b[tid]);
  else if (tid < Cp) Y[(long)row * Cp + tid] = 0;
}

// ---------------- MFMA flash attention: t-tile 128 (32 t-rows/wave), XCD-swizzled ----
// grid = 512 (= 2 blocks/CU), block 256. q pre-scaled by CLOG at projection.
// Each wave owns TWO 16-row t-groups (A/B) so the K/V LDS fragment reads, kr loads,
// staging and barriers amortize over 2x the output. P stays in registers via
// cvt_pk + permlane32/16_swap (no Ps buffer).  [r3/r6-verified config: 51.6-51.9 us]
#define KSTR 36
#define VSTR 68
__global__ __launch_bounds__(256, 2) void attn_mfma_kernel(
    const unsigned short* __restrict__ qn, const unsigned short* __restrict__ qr,
    const unsigned short* __restrict__ kn, const unsigned short* __restrict__ kr,
    const unsigned short* __restrict__ vT, unsigned short* __restrict__ ob)
{
  __shared__ unsigned short Kn[2][64 * KSTR];
  __shared__ unsigned short Vs[2][64 * VSTR];   // Vs[d][s]
  const int id = blockIdx.x;
  const int xcd = id & 7, j = id >> 3;          // j in 0..63
  const int bh = xcd * 4 + (j & 3);             // all 16 tiles of bh on one XCD
  const int tile = j >> 2;                      // 0..15
  const int b = bh >> 4, h = bh & 15;
  const int t0 = tile * 128;
  const int tid = threadIdx.x;
  const int w = tid >> 6, lane = tid & 63;
  const int ln16 = lane & 15, quad = lane >> 4;
  const int trow = w * 16;
  const long bT = (long)b * SEQ;

  // staging indices
  const int krow = tid >> 2, kc8 = (tid & 3) * 8;          // Kn: 64 rows x 32
  const int vd0 = tid >> 3, vc0 = (tid & 7) * 8;           // V: segs tid, tid+256
  const int vd1 = vd0 + 32;

  // Q fragments in registers: group A = rows t0+trow, group B = rows t0+64+trow
  bf16x8 q0A = *(const bf16x8*)&qn[(bT + t0 + trow + ln16) * 512 + h * 32 + quad * 8];
  bf16x8 q1A = *(const bf16x8*)&qr[(bT + t0 + trow + ln16) * 512 + h * 32 + quad * 8];
  bf16x8 q0B = *(const bf16x8*)&qn[(bT + t0 + 64 + trow + ln16) * 512 + h * 32 + quad * 8];
  bf16x8 q1B = *(const bf16x8*)&qr[(bT + t0 + 64 + trow + ln16) * 512 + h * 32 + quad * 8];

  auto loadKV = [&](int s0, bf16x8& rk0, bf16x8& rv0, bf16x8& rv1) {
    rk0 = *(const bf16x8*)&kn[(bT + s0 + krow) * 512 + h * 32 + kc8];
    rv0 = *(const bf16x8*)&vT[((long)bh * 64 + vd0) * SEQ + s0 + vc0];
    rv1 = *(const bf16x8*)&vT[((long)bh * 64 + vd1) * SEQ + s0 + vc0];
  };
  auto writeKV = [&](int ib, bf16x8 rk0, bf16x8 rv0, bf16x8 rv1) {
    *(bf16x8*)&Kn[ib][krow * KSTR + kc8] = rk0;
    *(bf16x8*)&Vs[ib][vd0 * VSTR + vc0] = rv0;
    *(bf16x8*)&Vs[ib][vd1 * VSTR + vc0] = rv1;
  };
  // kr A-fragments straight from global (L2-hot: shared by all h of this b)
  auto loadKrF = [&](int s0, bf16x8* f) {
#pragma unroll
    for (int nt = 0; nt < 4; ++nt)
      f[nt] = *(const bf16x8*)&kr[(bT + s0 + nt * 16 + ln16) * 32 + quad * 8];
  };
  // P transform: sf (4x f32x4, swapped-QK layout) -> two bf16x8 PV A-fragments
  auto pxform = [&](const f32x4* sf, float& l_part, bf16x8& a0, bf16x8& a1) {
    float p[16];
#pragma unroll
    for (int nt = 0; nt < 4; ++nt)
#pragma unroll
      for (int r = 0; r < 4; ++r) {
        const float e = EXP2(sf[nt][r]);
        p[nt * 4 + r] = e;
        l_part += e;
      }
    unsigned u0 = cvtpk(p[0],  p[1]),  u1 = cvtpk(p[2],  p[3]);
    unsigned u2 = cvtpk(p[4],  p[5]),  u3 = cvtpk(p[6],  p[7]);
    unsigned u4 = cvtpk(p[8],  p[9]),  u5 = cvtpk(p[10], p[11]);
    unsigned u6 = cvtpk(p[12], p[13]), u7 = cvtpk(p[14], p[15]);
    plswap32(u0, u2); plswap16(u0, u2);
    plswap32(u1, u3); plswap16(u1, u3);
    plswap32(u4, u6); plswap16(u4, u6);
    plswap32(u5, u7); plswap16(u5, u7);
    const uint4 w0 = make_uint4(u0, u1, u2, u3);   // P[t=ln16][s = 8q .. 8q+7]
    const uint4 w1 = make_uint4(u4, u5, u6, u7);   // P[t=ln16][s = 32+8q .. +7]
    a0 = __builtin_bit_cast(bf16x8, w0);
    a1 = __builtin_bit_cast(bf16x8, w1);
  };

  bf16x8 ck0, cv0, cv1;
  bf16x8 nk0, nv0, nv1;
  bf16x8 ckr[4];
  loadKV(0, ck0, cv0, cv1);
  writeKV(0, ck0, cv0, cv1);
  loadKV(64, nk0, nv0, nv1);
  loadKrF(0, ckr);

  f32x4 o_acc[2][4];
#pragma unroll
  for (int g = 0; g < 2; ++g)
#pragma unroll
    for (int nt = 0; nt < 4; ++nt)
#pragma unroll
      for (int r = 0; r < 4; ++r) o_acc[g][nt][r] = 0.0f;
  float l_part[2] = {0.0f, 0.0f};      // per-lane partials, groups A/B

  int ib = 0;
  for (int s0 = 0; s0 < SEQ; s0 += 64, ib ^= 1) {
    __syncthreads();
    if (s0 + 64 < SEQ) {
      writeKV(ib ^ 1, nk0, nv0, nv1);
      if (s0 + 128 < SEQ) loadKV(s0 + 128, nk0, nv0, nv1);
    }

    // K fragments: read ONCE, feed both t-groups
    bf16x8 ka[4];
#pragma unroll
    for (int nt = 0; nt < 4; ++nt)
      ka[nt] = *(const bf16x8*)&Kn[ib][(nt * 16 + ln16) * KSTR + quad * 8];

    // S^T = K @ Q^T for both groups
    f32x4 sfA[4], sfB[4];
#pragma unroll
    for (int nt = 0; nt < 4; ++nt)
#pragma unroll
      for (int r = 0; r < 4; ++r) { sfA[nt][r] = 0.0f; sfB[nt][r] = 0.0f; }
#pragma unroll
    for (int nt = 0; nt < 4; ++nt) {
      sfA[nt] = __builtin_amdgcn_mfma_f32_16x16x32_bf16(ka[nt], q0A, sfA[nt], 0, 0, 0);
      sfA[nt] = __builtin_amdgcn_mfma_f32_16x16x32_bf16(ckr[nt], q1A, sfA[nt], 0, 0, 0);
    }
#pragma unroll
    for (int nt = 0; nt < 4; ++nt) {
      sfB[nt] = __builtin_amdgcn_mfma_f32_16x16x32_bf16(ka[nt], q0B, sfB[nt], 0, 0, 0);
      sfB[nt] = __builtin_amdgcn_mfma_f32_16x16x32_bf16(ckr[nt], q1B, sfB[nt], 0, 0, 0);
    }

    // ckr consumed: reload for next s-tile (L2-hot; latency hidden by softmax+PV)
    if (s0 + 64 < SEQ) loadKrF(s0 + 64, ckr);

    bf16x8 a0A, a1A, a0B, a1B;
    pxform(sfA, l_part[0], a0A, a1A);
    pxform(sfB, l_part[1], a0B, a1B);

    // O += P(16 x 64) @ V(64 x 64), V fragments read ONCE for both groups
#pragma unroll
    for (int nt = 0; nt < 4; ++nt) {
      bf16x8 v0 = *(const bf16x8*)&Vs[ib][(nt * 16 + ln16) * VSTR + quad * 8];
      o_acc[0][nt] = __builtin_amdgcn_mfma_f32_16x16x32_bf16(a0A, v0, o_acc[0][nt], 0, 0, 0);
      o_acc[1][nt] = __builtin_amdgcn_mfma_f32_16x16x32_bf16(a0B, v0, o_acc[1][nt], 0, 0, 0);
      bf16x8 v1 = *(const bf16x8*)&Vs[ib][(nt * 16 + ln16) * VSTR + 32 + quad * 8];
      o_acc[0][nt] = __builtin_amdgcn_mfma_f32_16x16x32_bf16(a1A, v1, o_acc[0][nt], 0, 0, 0);
      o_acc[1][nt] = __builtin_amdgcn_mfma_f32_16x16x32_bf16(a1B, v1, o_acc[1][nt], 0, 0, 0);
    }
  }

  // per-group cross-quad l reduction + output
#pragma unroll
  for (int g = 0; g < 2; ++g) {
    float l_i = l_part[g];
    l_i += __shfl_xor(l_i, 16);
    l_i += __shfl_xor(l_i, 32);
    const float lr = 1.0f / l_i;
    float lq[4];
#pragma unroll
    for (int r = 0; r < 4; ++r) lq[r] = __shfl(lr, quad * 4 + r);
#pragma unroll
    for (int r = 0; r < 4; ++r) {
      const long t = t0 + g * 64 + trow + quad * 4 + r;
      const long base = (bT + t) * 1024 + h * 64 + ln16;
#pragma unroll
      for (int nt = 0; nt < 4; ++nt)
        ob[base + nt * 16] = f2bf(o_acc[g][nt][r] * lq[r]);
    }
  }
}

extern "C" void kernel_launch(void* const* d_in, const int* in_sizes, int n_in,
                              void* d_out, int out_size, void* d_ws, size_t ws_size,
                              hipStream_t stream) {
  const float* x       = (const float*)d_in[0];
  const float* xf      = (const float*)d_in[1];
  const float* Wqc     = (const float*)d_in[2];
  const float* gq      = (const float*)d_in[3];
  const float* bq      = (const float*)d_in[4];
  const float* Wq_rope = (const float*)d_in[5];   // rope before nope in dict order
  const float* Wq_nope = (const float*)d_in[6];
  const float* Wkvc    = (const float*)d_in[7];
  const float* gkv     = (const float*)d_in[8];
  const float* bkv     = (const float*)d_in[9];
  const float* Wk_nope = (const float*)d_in[10];
  const float* Wv      = (const float*)d_in[11];
  const float* Wkr     = (const float*)d_in[12];
  const float* Wo      = (const float*)d_in[13];
  const float* bo      = (const float*)d_in[14];
  float* out = (float*)d_out;

  const long R = 4096;
  float* ws = (float*)d_ws;
  float* ql_f  = ws;                       // 4096 x 256 f32
  float* kvl_f = ql_f + R * 256;           // 4096 x 256 f32
  float2* cst  = (float2*)(kvl_f + R * 256);  // 2048 x 16 cos/sin pairs
  unsigned short* us = (unsigned short*)(cst + 2048 * 16);
  unsigned short* ql_bf  = us;  us += R * 256;
  unsigned short* kvl_bf = us;  us += R * 224;    // K-padded to 224
  unsigned short* qn_bf  = us;  us += R * 512;
  unsigned short* qr_bf  = us;  us += R * 512;
  unsigned short* kn_bf  = us;  us += R * 512;
  unsigned short* kr_bf  = us;  us += R * 32;
  unsigned short* vT_bf  = us;  us += R * 1024;   // (B,H,64,S)
  unsigned short* o_bf   = us;  us += R * 1024;
  unsigned short* x_bf   = us;  us += R * 1024;   // x as bf16
  unsigned short* xf_bf  = us;  us += R * 1024;   // xf as bf16
  unsigned short* WqcT   = us;  us += 256 * 1024;
  unsigned short* WkvkrT = us;  us += 384 * 1024; // [Wkvc^T pad256 | Wkr^T pad128]
  unsigned short* WqnqrT = us;  us += 1024 * 256; // [Wq_nope^T | Wq_rope^T]
  unsigned short* WknvT  = us;  us += 1536 * 224; // [Wk_nope^T | Wv^T], K pad 224
  unsigned short* WoT    = us;  us += 1024 * 1024;

  // 0) mega prep: rope table + x/xf bf16 convert + 8 weight transposes
  WPrep p;
  const float* srcs[8] = {Wqc, Wkvc, Wkr, Wq_nope, Wq_rope, Wk_nope, Wv, Wo};
  unsigned short* dsts[8] = {WqcT, WkvkrT, WkvkrT + 256 * 1024,
                             WqnqrT, WqnqrT + 512 * 256,
                             WknvT, WknvT + 512 * 224, WoT};
  const int Ks[8]  = {1024, 1024, 1024, 256, 256, 204, 204, 1024};
  const int Ns[8]  = {256, 204, 32, 512, 512, 512, 1024, 1024};
  const int NRs[8] = {256, 256, 128, 512, 512, 512, 1024, 1024};
  const int KCs[8] = {1024, 1024, 1024, 256, 256, 224, 224, 1024};
  int total = 128 + 4096;
  for (int i = 0; i < 8; ++i) {
    p.src[i] = srcs[i]; p.dst[i] = dsts[i];
    p.K[i] = Ks[i]; p.N[i] = Ns[i]; p.NR[i] = NRs[i]; p.KC[i] = KCs[i];
    p.nb[i] = (KCs[i] / 32) * (NRs[i] / 32);
    total += p.nb[i];
  }
  p.cst = cst;
  p.xs[0] = x;  p.xs[1] = xf;
  p.xd[0] = x_bf; p.xd[1] = xf_bf;
  wprep_kernel<<<total, 256, 0, stream>>>(p);

  // 1) dual 64x128-tile GEMM (deep K=1024): z=0 ql_f = x @ Wqc ;
  //    z=1 [kvl | kr] = xf @ [Wkvc | Wkr] (+rope/16)
  gemm_dualw<0, 4><<<dim3(3, 64, 2), 256, 0, stream>>>(
      x_bf, WqcT, ql_f, nullptr, 1024, 256, 2,
      xf_bf, WkvkrT, kvl_f, kr_bf, 1024, 384, cst);
  // 2) merged LN
  ln2_kernel<<<8192, 256, 0, stream>>>(ql_f, kvl_f, gq, bq, gkv, bkv, ql_bf, kvl_bf);
  // 3) dual 128-tile GEMM (short K, wide N): z=0 [qn|qr] (+rope, *CLOG) ; z=1 [kn|vT]
  gemm_dual<3, false, 5, false><<<dim3(12, 32, 2), 256, 0, stream>>>(
      ql_bf, WqnqrT, qn_bf, qr_bf, 256, 1024, 8,
      kvl_bf, WknvT, kn_bf, vT_bf, 224, 1536, cst);
  // 4) attention -> o bf16 (r3/r6 config: t-tile 128, KVBLK 64, 2 blocks/CU)
  attn_mfma_kernel<<<512, 256, 0, stream>>>(qn_bf, qr_bf, kn_bf, kr_bf, vT_bf, o_bf);
  // 5) out = o @ Wo + bo (fp32), 64x128-tile deep-K: 512 blocks = 2/CU
  gemm_widek<1><<<dim3(8, 64), 256, 0, stream>>>(o_bf, WoT, bo, cst, out, nullptr, 1024, 1024);
}

// Round 9
// 208.344 us; speedup vs baseline: 1.3117x; 1.0153x over previous
//
#include <hip/hip_runtime.h>
#include <hip/hip_bf16.h>
#include <math.h>

#define SEQ 2048

typedef __bf16 bf16x8 __attribute__((ext_vector_type(8)));
typedef float  f32x4  __attribute__((ext_vector_type(4)));

#if __has_builtin(__builtin_amdgcn_exp2f)
#define EXP2(x) __builtin_amdgcn_exp2f(x)
#else
#define EXP2(x) exp2f(x)
#endif

__device__ __forceinline__ unsigned short f2bf(float f) {
  __bf16 h = (__bf16)f;
  return __builtin_bit_cast(unsigned short, h);
}

__device__ __forceinline__ void gload16(const unsigned short* g, unsigned short* l) {
  __builtin_amdgcn_global_load_lds(
      (const __attribute__((address_space(1))) void*)g,
      (__attribute__((address_space(3))) void*)l, 16, 0, 0);
}

// packed f32->bf16 convert (RNE, same rounding as scalar (__bf16) cast)
__device__ __forceinline__ unsigned cvtpk(float lo, float hi) {
  unsigned r;
  asm("v_cvt_pk_bf16_f32 %0, %1, %2" : "=v"(r) : "v"(lo), "v"(hi));
  return r;
}
// a[32:63] <-> b[0:31]:  a' = [a_q0,a_q1,b_q0,b_q1], b' = [a_q2,a_q3,b_q2,b_q3]
__device__ __forceinline__ void plswap32(unsigned &a, unsigned &b) {
  asm("v_permlane32_swap_b32 %0, %1" : "+v"(a), "+v"(b));
}
// odd 16-rows of a <-> even 16-rows of b: a' = [a0,b0,a2,b2], b' = [a1,b1,a3,b3]
__device__ __forceinline__ void plswap16(unsigned &a, unsigned &b) {
  asm("v_permlane16_swap_b32 %0, %1" : "+v"(a), "+v"(b));
}

#define CLOG (0.125f * 1.44269504f)   // 1/sqrt(HD) * log2(e), folded into q

// ===== mega prep: rope table + x/xf f32->bf16 convert + 8 weight transposes =====
struct WPrep {
  const float* src[8];
  unsigned short* dst[8];
  int K[8], N[8], NR[8], KC[8], nb[8];
  float2* cst;
  const float* xs[2];
  unsigned short* xd[2];
};

__global__ __launch_bounds__(256) void wprep_kernel(WPrep p)
{
  __shared__ float tile[32][33];
  int bid = blockIdx.x;
  if (bid < 128) {                       // rope table: 32768 entries
    const int idx = bid * 256 + threadIdx.x;
    const int pos = idx >> 4, i = idx & 15;
    const float freq = EXP2(-(float)i * 0.8304820237f);
    const float ang = (float)pos * freq;
    p.cst[idx] = make_float2(cosf(ang), sinf(ang));
    return;
  }
  bid -= 128;
  if (bid < 4096) {                      // x/xf f32 -> bf16 (2048 blocks each)
    const int sel = bid >> 11;
    const long base = (long)(bid & 2047) * 2048 + threadIdx.x * 8;
    const float4 a = *(const float4*)&p.xs[sel][base];
    const float4 b = *(const float4*)&p.xs[sel][base + 4];
    ushort4 u0, u1;
    u0.x = f2bf(a.x); u0.y = f2bf(a.y); u0.z = f2bf(a.z); u0.w = f2bf(a.w);
    u1.x = f2bf(b.x); u1.y = f2bf(b.y); u1.z = f2bf(b.z); u1.w = f2bf(b.w);
    *(ushort4*)&p.xd[sel][base] = u0;
    *(ushort4*)&p.xd[sel][base + 4] = u1;
    return;
  }
  bid -= 4096;
  int di = 0;
  while (bid >= p.nb[di]) { bid -= p.nb[di]; ++di; }
  const float* src = p.src[di];
  unsigned short* dst = p.dst[di];
  const int K = p.K[di], N = p.N[di], KC = p.KC[di];
  const int nkx = KC >> 5;
  const int k0 = (bid % nkx) * 32, n0 = (bid / nkx) * 32;
  const int tx = threadIdx.x & 31, ty = threadIdx.x >> 5;
  for (int r = ty; r < 32; r += 8) {
    const int k = k0 + r, n = n0 + tx;
    tile[r][tx] = (k < K && n < N) ? src[(long)k * N + n] : 0.0f;
  }
  __syncthreads();
  for (int r = ty; r < 32; r += 8) {
    const int n = n0 + r, k = k0 + tx;
    dst[(long)n * KC + k] = f2bf(tile[tx][r]);
  }
}

// ============ 128-tile bf16 MFMA GEMM body (for wide-N, short-K GEMMs) ============
// EPI: 3 QROPE: cols<512 -> qn (*CLOG); cols>=512 rope -> qr (*CLOG)   [stride 512]
//      5 KNV:   cols<512 -> kn (stride 512); cols>=512 -> vT (B,H,64,S) via LDS transpose
template <int EPI, bool AF32>
__device__ __forceinline__ void gemm_body(
    unsigned short* smem,                     // 16896 shorts
    const void* __restrict__ Av, const unsigned short* __restrict__ BT,
    const float* __restrict__ bias, const float2* __restrict__ cst,
    void* __restrict__ C0v, void* __restrict__ C1v, int K, int N,
    int bx, int by)
{
  unsigned short* As = smem;               // [2][128*32]
  unsigned short* Bs = smem + 2 * 128 * 32;
  const int tid = threadIdx.x;
  const int w = tid >> 6, lane = tid & 63;
  const int ln16 = lane & 15, quad = lane >> 4;
  const int wm = (w >> 1) * 64, wn = (w & 1) * 64;
  const int m0 = by * 128, n0 = bx * 128;
  const int rr = tid >> 2, cc = (tid & 3) * 8;

  const unsigned short* A = (const unsigned short*)Av;

  auto stageB = [&](int ib, int k0) {
    gload16(&BT[(long)(n0 + rr)      * K + k0 + cc], &Bs[ib * 4096 + rr * 32 + cc]);
    gload16(&BT[(long)(n0 + 64 + rr) * K + k0 + cc], &Bs[ib * 4096 + (64 + rr) * 32 + cc]);
  };
  auto stageAbf = [&](int ib, int k0) {
    gload16(&A[(long)(m0 + rr)      * K + k0 + cc], &As[ib * 4096 + rr * 32 + cc]);
    gload16(&A[(long)(m0 + 64 + rr) * K + k0 + cc], &As[ib * 4096 + (64 + rr) * 32 + cc]);
  };

  f32x4 acc[4][4];
#pragma unroll
  for (int i = 0; i < 4; ++i)
#pragma unroll
    for (int j = 0; j < 4; ++j)
#pragma unroll
      for (int r = 0; r < 4; ++r) acc[i][j][r] = 0.0f;

  stageB(0, 0);
  stageAbf(0, 0);

  int ib = 0;
  for (int k0 = 0; k0 < K; k0 += 32, ib ^= 1) {
    __syncthreads();
    const int kn = k0 + 32;
    if (kn < K) { stageB(ib ^ 1, kn); stageAbf(ib ^ 1, kn); }
    bf16x8 fa[4], fb[4];
#pragma unroll
    for (int i = 0; i < 4; ++i) fa[i] = *(const bf16x8*)&As[ib * 4096 + (wm + i * 16 + ln16) * 32 + quad * 8];
#pragma unroll
    for (int j = 0; j < 4; ++j) fb[j] = *(const bf16x8*)&Bs[ib * 4096 + (wn + j * 16 + ln16) * 32 + quad * 8];
#pragma unroll
    for (int i = 0; i < 4; ++i)
#pragma unroll
      for (int j = 0; j < 4; ++j)
        acc[i][j] = __builtin_amdgcn_mfma_f32_16x16x32_bf16(fa[i], fb[j], acc[i][j], 0, 0, 0);
  }

  // ----- epilogues -----
  if (EPI == 5 && n0 >= 512) {
    // fused V transpose: acc tile (128 s-rows x 128 cols) -> vT (B,H,64,S) coalesced
    __syncthreads();
#pragma unroll
    for (int i = 0; i < 4; ++i) {
      const int rl = wm + i * 16 + quad * 4;
#pragma unroll
      for (int j = 0; j < 4; ++j) {
        const int cl = wn + j * 16 + ln16;
        ushort4 u;
        u.x = f2bf(acc[i][j][0]); u.y = f2bf(acc[i][j][1]);
        u.z = f2bf(acc[i][j][2]); u.w = f2bf(acc[i][j][3]);
        *(ushort4*)&smem[cl * 132 + rl] = u;
      }
    }
    __syncthreads();
    unsigned short* vT = (unsigned short*)C1v;
    const int b = m0 >> 11, sbase = m0 & (SEQ - 1);
    for (int q = tid; q < 128 * 16; q += 256) {
      const int cl = q >> 4, sch = (q & 15) * 8;
      bf16x8 val = *(const bf16x8*)&smem[cl * 132 + sch];
      const int c = (n0 - 512) + cl;
      const int hh = c >> 6, dd = c & 63;
      *(bf16x8*)&vT[((long)(b * 16 + hh) * 64 + dd) * SEQ + sbase + sch] = val;
    }
    return;
  }
#pragma unroll
  for (int i = 0; i < 4; ++i) {
    const int row0 = m0 + wm + i * 16 + quad * 4;
#pragma unroll
    for (int j = 0; j < 4; ++j) {
      const int col = n0 + wn + j * 16 + ln16;
      if (EPI == 3) {
        if (n0 < 512) {
          unsigned short* qn = (unsigned short*)C0v;
#pragma unroll
          for (int r = 0; r < 4; ++r) qn[(long)(row0 + r) * 512 + col] = f2bf(acc[i][j][r] * CLOG);
        } else {
          unsigned short* qr = (unsigned short*)C1v;
          const int c = col - 512;
          const int d = c & 31;
#pragma unroll
          for (int r = 0; r < 4; ++r) {
            const float v = acc[i][j][r];
            const float p = __shfl_xor(v, 1);
            const float2 t = cst[((row0 + r) & (SEQ - 1)) * 16 + (d >> 1)];
            const float o = ((d & 1) == 0) ? (v * t.x - p * t.y) : (p * t.y + v * t.x);
            qr[(long)(row0 + r) * 512 + c] = f2bf(o * CLOG);
          }
        }
      } else if (EPI == 5) {
        unsigned short* kn = (unsigned short*)C0v;
#pragma unroll
        for (int r = 0; r < 4; ++r) kn[(long)(row0 + r) * 512 + col] = f2bf(acc[i][j][r]);
      }
    }
  }
}

// dual 128-tile wrapper, exact 1-D grid (no idle blocks)
template <int E0, bool AF0, int E1, bool AF1>
__global__ __launch_bounds__(256) void gemm_dual1d(
    const void* __restrict__ A0, const unsigned short* __restrict__ BT0,
    void* __restrict__ C00, void* __restrict__ C01, int K0, int N0, int nx0, int nb0,
    const void* __restrict__ A1, const unsigned short* __restrict__ BT1,
    void* __restrict__ C10, void* __restrict__ C11, int K1, int N1, int nx1,
    const float2* __restrict__ cst)
{
  __shared__ unsigned short smem[16896];
  int bid = blockIdx.x;
  if (bid < nb0) {
    gemm_body<E0, AF0>(smem, A0, BT0, nullptr, cst, C00, C01, K0, N0, bid % nx0, bid / nx0);
  } else {
    bid -= nb0;
    gemm_body<E1, AF1>(smem, A1, BT1, nullptr, cst, C10, C11, K1, N1, bid % nx1, bid / nx1);
  }
}

// ============ 64x128-tile bf16 GEMM body (deep-K; 8 MFMA/K-step/wave) ==============
// EPI: 0 f32->C0 ; 1 f32+bias->C0 ; 4 KVKR: cols<256 f32->kvl ; cols 256..287 rope/16->kr
template <int EPI>
__device__ __forceinline__ void gemm_wbody(
    unsigned short* smem,                     // 12288 shorts
    const unsigned short* __restrict__ A, const unsigned short* __restrict__ BT,
    const float* __restrict__ bias, const float2* __restrict__ cst,
    void* __restrict__ C0v, void* __restrict__ C1v, int K, int N,
    int bx, int by)
{
  unsigned short* As = smem;               // [2][64*32]
  unsigned short* Bs = smem + 4096;        // [2][128*32]
  const int tid = threadIdx.x;
  const int w = tid >> 6, lane = tid & 63;
  const int ln16 = lane & 15, quad = lane >> 4;
  const int wm = (w >> 1) * 32, wn = (w & 1) * 64;
  const int m0 = by * 64, n0 = bx * 128;
  const int rr = tid >> 2, cc = (tid & 3) * 8;

  auto stageA = [&](int ib, int k0) {
    gload16(&A[(long)(m0 + rr) * K + k0 + cc], &As[ib * 2048 + rr * 32 + cc]);
  };
  auto stageB = [&](int ib, int k0) {
    gload16(&BT[(long)(n0 + rr)      * K + k0 + cc], &Bs[ib * 4096 + rr * 32 + cc]);
    gload16(&BT[(long)(n0 + 64 + rr) * K + k0 + cc], &Bs[ib * 4096 + (64 + rr) * 32 + cc]);
  };

  f32x4 acc[2][4];
#pragma unroll
  for (int i = 0; i < 2; ++i)
#pragma unroll
    for (int j = 0; j < 4; ++j)
#pragma unroll
      for (int r = 0; r < 4; ++r) acc[i][j][r] = 0.0f;

  stageA(0, 0);
  stageB(0, 0);

  int ib = 0;
  for (int k0 = 0; k0 < K; k0 += 32, ib ^= 1) {
    __syncthreads();
    const int kn = k0 + 32;
    if (kn < K) { stageA(ib ^ 1, kn); stageB(ib ^ 1, kn); }
    bf16x8 fa[2], fb[4];
#pragma unroll
    for (int i = 0; i < 2; ++i) fa[i] = *(const bf16x8*)&As[ib * 2048 + (wm + i * 16 + ln16) * 32 + quad * 8];
#pragma unroll
    for (int j = 0; j < 4; ++j) fb[j] = *(const bf16x8*)&Bs[ib * 4096 + (wn + j * 16 + ln16) * 32 + quad * 8];
#pragma unroll
    for (int i = 0; i < 2; ++i)
#pragma unroll
      for (int j = 0; j < 4; ++j)
        acc[i][j] = __builtin_amdgcn_mfma_f32_16x16x32_bf16(fa[i], fb[j], acc[i][j], 0, 0, 0);
  }

#pragma unroll
  for (int i = 0; i < 2; ++i) {
    const int row0 = m0 + wm + i * 16 + quad * 4;
#pragma unroll
    for (int j = 0; j < 4; ++j) {
      const int col = n0 + wn + j * 16 + ln16;
      if (EPI == 0 || EPI == 1) {
        float* C = (float*)C0v;
        const float bv = (EPI == 1) ? bias[col] : 0.0f;
#pragma unroll
        for (int r = 0; r < 4; ++r) C[(long)(row0 + r) * N + col] = acc[i][j][r] + bv;
      } else if (EPI == 4) {
        if (col < 256) {
          float* kvl = (float*)C0v;
#pragma unroll
          for (int r = 0; r < 4; ++r) kvl[(long)(row0 + r) * 256 + col] = acc[i][j][r];
        } else if (col < 288) {             // kr cols 256..287 (rope/16)
          unsigned short* kr = (unsigned short*)C1v;
          const int d = col - 256;          // 0..31
#pragma unroll
          for (int r = 0; r < 4; ++r) {
            const float v = acc[i][j][r];
            const float p = __shfl_xor(v, 1);
            const float2 t = cst[((row0 + r) & (SEQ - 1)) * 16 + (d >> 1)];
            const float o = ((d & 1) == 0) ? (v * t.x - p * t.y) : (p * t.y + v * t.x);
            kr[(long)(row0 + r) * 32 + d] = f2bf(o * 0.0625f);
          }
        }
      }
    }
  }
}

template <int EPI>
__global__ __launch_bounds__(256) void gemm_widek(
    const unsigned short* __restrict__ A, const unsigned short* __restrict__ BT,
    const float* __restrict__ bias, const float2* __restrict__ cst,
    void* __restrict__ C0, void* __restrict__ C1, int K, int N)
{
  __shared__ unsigned short smem[12288];
  gemm_wbody<EPI>(smem, A, BT, bias, cst, C0, C1, K, N, blockIdx.x, blockIdx.y);
}

// dual wide wrapper, exact 1-D grid (no idle blocks)
template <int E0, int E1>
__global__ __launch_bounds__(256) void gemm_dualw1d(
    const unsigned short* __restrict__ A0, const unsigned short* __restrict__ BT0,
    void* __restrict__ C00, void* __restrict__ C01, int K0, int N0, int nx0, int nb0,
    const unsigned short* __restrict__ A1, const unsigned short* __restrict__ BT1,
    void* __restrict__ C10, void* __restrict__ C11, int K1, int N1, int nx1,
    const float2* __restrict__ cst)
{
  __shared__ unsigned short smem[12288];
  int bid = blockIdx.x;
  if (bid < nb0) {
    gemm_wbody<E0>(smem, A0, BT0, nullptr, cst, C00, C01, K0, N0, bid % nx0, bid / nx0);
  } else {
    bid -= nb0;
    gemm_wbody<E1>(smem, A1, BT1, nullptr, cst, C10, C11, K1, N1, bid % nx1, bid / nx1);
  }
}

// ---- fast merged LayerNorm: 1 row per WAVE, 4 rows/block, no LDS/barriers --------
// rows 0..4095 -> ql (C=256), 4096..8191 -> kvl (C=204, padded to 224)
__global__ __launch_bounds__(256) void ln_fast_kernel(
    const float* __restrict__ Xq, const float* __restrict__ Xkv,
    const float* __restrict__ gq, const float* __restrict__ bq,
    const float* __restrict__ gkv, const float* __restrict__ bkv,
    unsigned short* __restrict__ Yq, unsigned short* __restrict__ Ykv)
{
  const int tid = threadIdx.x;
  const int wv = tid >> 6, lane = tid & 63;
  const int row0 = blockIdx.x * 4 + wv;          // 0..8191
  const bool isq = row0 < 4096;
  const int row = isq ? row0 : row0 - 4096;
  const float* X = isq ? Xq : Xkv;
  const float* g = isq ? gq : gkv;
  const float* b = isq ? bq : bkv;
  unsigned short* Y = isq ? Yq : Ykv;
  const int C = isq ? 256 : 204;                 // both divisible by 4
  const int Cp = isq ? 256 : 224;
  const int col = lane * 4;
  const bool valid = col < C;                    // whole-float4 validity (C%4==0)
  float4 v = make_float4(0.f, 0.f, 0.f, 0.f);
  if (valid) v = *(const float4*)&X[(long)row * 256 + col];
  float s1 = v.x + v.y + v.z + v.w;
  float s2 = v.x * v.x + v.y * v.y + v.z * v.z + v.w * v.w;
#pragma unroll
  for (int off = 1; off < 64; off <<= 1) {
    s1 += __shfl_xor(s1, off);
    s2 += __shfl_xor(s2, off);
  }
  const float mean = s1 / C;
  const float var  = s2 / C - mean * mean;
  const float rs = rsqrtf(var + 1e-5f);
  if (valid) {
    const float4 gv = *(const float4*)&g[col];
    const float4 bv = *(const float4*)&b[col];
    ushort4 u;
    u.x = f2bf((v.x - mean) * rs * gv.x + bv.x);
    u.y = f2bf((v.y - mean) * rs * gv.y + bv.y);
    u.z = f2bf((v.z - mean) * rs * gv.z + bv.z);
    u.w = f2bf((v.w - mean) * rs * gv.w + bv.w);
    *(ushort4*)&Y[(long)row * Cp + col] = u;
  } else if (col < Cp) {
    *(ushort4*)&Y[(long)row * Cp + col] = make_ushort4(0, 0, 0, 0);
  }
}

// ---------------- MFMA flash attention: t-tile 128 (32 t-rows/wave), XCD-swizzled ----
// grid = 512 (= 2 blocks/CU), block 256. q pre-scaled by CLOG at projection.
// Each wave owns TWO 16-row t-groups (A/B) so the K/V LDS fragment reads, kr loads,
// staging and barriers amortize over 2x the output. P stays in registers via
// cvt_pk + permlane32/16_swap (no Ps buffer).  [r3/r6/r8-verified: 51.6-51.9 us]
#define KSTR 36
#define VSTR 68
__global__ __launch_bounds__(256, 2) void attn_mfma_kernel(
    const unsigned short* __restrict__ qn, const unsigned short* __restrict__ qr,
    const unsigned short* __restrict__ kn, const unsigned short* __restrict__ kr,
    const unsigned short* __restrict__ vT, unsigned short* __restrict__ ob)
{
  __shared__ unsigned short Kn[2][64 * KSTR];
  __shared__ unsigned short Vs[2][64 * VSTR];   // Vs[d][s]
  const int id = blockIdx.x;
  const int xcd = id & 7, j = id >> 3;          // j in 0..63
  const int bh = xcd * 4 + (j & 3);             // all 16 tiles of bh on one XCD
  const int tile = j >> 2;                      // 0..15
  const int b = bh >> 4, h = bh & 15;
  const int t0 = tile * 128;
  const int tid = threadIdx.x;
  const int w = tid >> 6, lane = tid & 63;
  const int ln16 = lane & 15, quad = lane >> 4;
  const int trow = w * 16;
  const long bT = (long)b * SEQ;

  // staging indices
  const int krow = tid >> 2, kc8 = (tid & 3) * 8;          // Kn: 64 rows x 32
  const int vd0 = tid >> 3, vc0 = (tid & 7) * 8;           // V: segs tid, tid+256
  const int vd1 = vd0 + 32;

  // Q fragments in registers: group A = rows t0+trow, group B = rows t0+64+trow
  bf16x8 q0A = *(const bf16x8*)&qn[(bT + t0 + trow + ln16) * 512 + h * 32 + quad * 8];
  bf16x8 q1A = *(const bf16x8*)&qr[(bT + t0 + trow + ln16) * 512 + h * 32 + quad * 8];
  bf16x8 q0B = *(const bf16x8*)&qn[(bT + t0 + 64 + trow + ln16) * 512 + h * 32 + quad * 8];
  bf16x8 q1B = *(const bf16x8*)&qr[(bT + t0 + 64 + trow + ln16) * 512 + h * 32 + quad * 8];

  auto loadKV = [&](int s0, bf16x8& rk0, bf16x8& rv0, bf16x8& rv1) {
    rk0 = *(const bf16x8*)&kn[(bT + s0 + krow) * 512 + h * 32 + kc8];
    rv0 = *(const bf16x8*)&vT[((long)bh * 64 + vd0) * SEQ + s0 + vc0];
    rv1 = *(const bf16x8*)&vT[((long)bh * 64 + vd1) * SEQ + s0 + vc0];
  };
  auto writeKV = [&](int ib, bf16x8 rk0, bf16x8 rv0, bf16x8 rv1) {
    *(bf16x8*)&Kn[ib][krow * KSTR + kc8] = rk0;
    *(bf16x8*)&Vs[ib][vd0 * VSTR + vc0] = rv0;
    *(bf16x8*)&Vs[ib][vd1 * VSTR + vc0] = rv1;
  };
  // kr A-fragments straight from global (L2-hot: shared by all h of this b)
  auto loadKrF = [&](int s0, bf16x8* f) {
#pragma unroll
    for (int nt = 0; nt < 4; ++nt)
      f[nt] = *(const bf16x8*)&kr[(bT + s0 + nt * 16 + ln16) * 32 + quad * 8];
  };
  // P transform: sf (4x f32x4, swapped-QK layout) -> two bf16x8 PV A-fragments
  auto pxform = [&](const f32x4* sf, float& l_part, bf16x8& a0, bf16x8& a1) {
    float p[16];
#pragma unroll
    for (int nt = 0; nt < 4; ++nt)
#pragma unroll
      for (int r = 0; r < 4; ++r) {
        const float e = EXP2(sf[nt][r]);
        p[nt * 4 + r] = e;
        l_part += e;
      }
    unsigned u0 = cvtpk(p[0],  p[1]),  u1 = cvtpk(p[2],  p[3]);
    unsigned u2 = cvtpk(p[4],  p[5]),  u3 = cvtpk(p[6],  p[7]);
    unsigned u4 = cvtpk(p[8],  p[9]),  u5 = cvtpk(p[10], p[11]);
    unsigned u6 = cvtpk(p[12], p[13]), u7 = cvtpk(p[14], p[15]);
    plswap32(u0, u2); plswap16(u0, u2);
    plswap32(u1, u3); plswap16(u1, u3);
    plswap32(u4, u6); plswap16(u4, u6);
    plswap32(u5, u7); plswap16(u5, u7);
    const uint4 w0 = make_uint4(u0, u1, u2, u3);   // P[t=ln16][s = 8q .. 8q+7]
    const uint4 w1 = make_uint4(u4, u5, u6, u7);   // P[t=ln16][s = 32+8q .. +7]
    a0 = __builtin_bit_cast(bf16x8, w0);
    a1 = __builtin_bit_cast(bf16x8, w1);
  };

  bf16x8 ck0, cv0, cv1;
  bf16x8 nk0, nv0, nv1;
  bf16x8 ckr[4];
  loadKV(0, ck0, cv0, cv1);
  writeKV(0, ck0, cv0, cv1);
  loadKV(64, nk0, nv0, nv1);
  loadKrF(0, ckr);

  f32x4 o_acc[2][4];
#pragma unroll
  for (int g = 0; g < 2; ++g)
#pragma unroll
    for (int nt = 0; nt < 4; ++nt)
#pragma unroll
      for (int r = 0; r < 4; ++r) o_acc[g][nt][r] = 0.0f;
  float l_part[2] = {0.0f, 0.0f};      // per-lane partials, groups A/B

  int ib = 0;
  for (int s0 = 0; s0 < SEQ; s0 += 64, ib ^= 1) {
    __syncthreads();
    if (s0 + 64 < SEQ) {
      writeKV(ib ^ 1, nk0, nv0, nv1);
      if (s0 + 128 < SEQ) loadKV(s0 + 128, nk0, nv0, nv1);
    }

    // K fragments: read ONCE, feed both t-groups
    bf16x8 ka[4];
#pragma unroll
    for (int nt = 0; nt < 4; ++nt)
      ka[nt] = *(const bf16x8*)&Kn[ib][(nt * 16 + ln16) * KSTR + quad * 8];

    // S^T = K @ Q^T for both groups
    f32x4 sfA[4], sfB[4];
#pragma unroll
    for (int nt = 0; nt < 4; ++nt)
#pragma unroll
      for (int r = 0; r < 4; ++r) { sfA[nt][r] = 0.0f; sfB[nt][r] = 0.0f; }
#pragma unroll
    for (int nt = 0; nt < 4; ++nt) {
      sfA[nt] = __builtin_amdgcn_mfma_f32_16x16x32_bf16(ka[nt], q0A, sfA[nt], 0, 0, 0);
      sfA[nt] = __builtin_amdgcn_mfma_f32_16x16x32_bf16(ckr[nt], q1A, sfA[nt], 0, 0, 0);
    }
#pragma unroll
    for (int nt = 0; nt < 4; ++nt) {
      sfB[nt] = __builtin_amdgcn_mfma_f32_16x16x32_bf16(ka[nt], q0B, sfB[nt], 0, 0, 0);
      sfB[nt] = __builtin_amdgcn_mfma_f32_16x16x32_bf16(ckr[nt], q1B, sfB[nt], 0, 0, 0);
    }

    // ckr consumed: reload for next s-tile (L2-hot; latency hidden by softmax+PV)
    if (s0 + 64 < SEQ) loadKrF(s0 + 64, ckr);

    bf16x8 a0A, a1A, a0B, a1B;
    pxform(sfA, l_part[0], a0A, a1A);
    pxform(sfB, l_part[1], a0B, a1B);

    // O += P(16 x 64) @ V(64 x 64), V fragments read ONCE for both groups
#pragma unroll
    for (int nt = 0; nt < 4; ++nt) {
      bf16x8 v0 = *(const bf16x8*)&Vs[ib][(nt * 16 + ln16) * VSTR + quad * 8];
      o_acc[0][nt] = __builtin_amdgcn_mfma_f32_16x16x32_bf16(a0A, v0, o_acc[0][nt], 0, 0, 0);
      o_acc[1][nt] = __builtin_amdgcn_mfma_f32_16x16x32_bf16(a0B, v0, o_acc[1][nt], 0, 0, 0);
      bf16x8 v1 = *(const bf16x8*)&Vs[ib][(nt * 16 + ln16) * VSTR + 32 + quad * 8];
      o_acc[0][nt] = __builtin_amdgcn_mfma_f32_16x16x32_bf16(a1A, v1, o_acc[0][nt], 0, 0, 0);
      o_acc[1][nt] = __builtin_amdgcn_mfma_f32_16x16x32_bf16(a1B, v1, o_acc[1][nt], 0, 0, 0);
    }
  }

  // per-group cross-quad l reduction + output
#pragma unroll
  for (int g = 0; g < 2; ++g) {
    float l_i = l_part[g];
    l_i += __shfl_xor(l_i, 16);
    l_i += __shfl_xor(l_i, 32);
    const float lr = 1.0f / l_i;
    float lq[4];
#pragma unroll
    for (int r = 0; r < 4; ++r) lq[r] = __shfl(lr, quad * 4 + r);
#pragma unroll
    for (int r = 0; r < 4; ++r) {
      const long t = t0 + g * 64 + trow + quad * 4 + r;
      const long base = (bT + t) * 1024 + h * 64 + ln16;
#pragma unroll
      for (int nt = 0; nt < 4; ++nt)
        ob[base + nt * 16] = f2bf(o_acc[g][nt][r] * lq[r]);
    }
  }
}

extern "C" void kernel_launch(void* const* d_in, const int* in_sizes, int n_in,
                              void* d_out, int out_size, void* d_ws, size_t ws_size,
                              hipStream_t stream) {
  const float* x       = (const float*)d_in[0];
  const float* xf      = (const float*)d_in[1];
  const float* Wqc     = (const float*)d_in[2];
  const float* gq      = (const float*)d_in[3];
  const float* bq      = (const float*)d_in[4];
  const float* Wq_rope = (const float*)d_in[5];   // rope before nope in dict order
  const float* Wq_nope = (const float*)d_in[6];
  const float* Wkvc    = (const float*)d_in[7];
  const float* gkv     = (const float*)d_in[8];
  const float* bkv     = (const float*)d_in[9];
  const float* Wk_nope = (const float*)d_in[10];
  const float* Wv      = (const float*)d_in[11];
  const float* Wkr     = (const float*)d_in[12];
  const float* Wo      = (const float*)d_in[13];
  const float* bo      = (const float*)d_in[14];
  float* out = (float*)d_out;

  const long R = 4096;
  float* ws = (float*)d_ws;
  float* ql_f  = ws;                       // 4096 x 256 f32
  float* kvl_f = ql_f + R * 256;           // 4096 x 256 f32
  float2* cst  = (float2*)(kvl_f + R * 256);  // 2048 x 16 cos/sin pairs
  unsigned short* us = (unsigned short*)(cst + 2048 * 16);
  unsigned short* ql_bf  = us;  us += R * 256;
  unsigned short* kvl_bf = us;  us += R * 224;    // K-padded to 224
  unsigned short* qn_bf  = us;  us += R * 512;
  unsigned short* qr_bf  = us;  us += R * 512;
  unsigned short* kn_bf  = us;  us += R * 512;
  unsigned short* kr_bf  = us;  us += R * 32;
  unsigned short* vT_bf  = us;  us += R * 1024;   // (B,H,64,S)
  unsigned short* o_bf   = us;  us += R * 1024;
  unsigned short* x_bf   = us;  us += R * 1024;   // x as bf16
  unsigned short* xf_bf  = us;  us += R * 1024;   // xf as bf16
  unsigned short* WqcT   = us;  us += 256 * 1024;
  unsigned short* WkvkrT = us;  us += 384 * 1024; // [Wkvc^T pad256 | Wkr^T pad128]
  unsigned short* WqnqrT = us;  us += 1024 * 256; // [Wq_nope^T | Wq_rope^T]
  unsigned short* WknvT  = us;  us += 1536 * 224; // [Wk_nope^T | Wv^T], K pad 224
  unsigned short* WoT    = us;  us += 1024 * 1024;

  // 0) mega prep: rope table + x/xf bf16 convert + 8 weight transposes
  WPrep p;
  const float* srcs[8] = {Wqc, Wkvc, Wkr, Wq_nope, Wq_rope, Wk_nope, Wv, Wo};
  unsigned short* dsts[8] = {WqcT, WkvkrT, WkvkrT + 256 * 1024,
                             WqnqrT, WqnqrT + 512 * 256,
                             WknvT, WknvT + 512 * 224, WoT};
  const int Ks[8]  = {1024, 1024, 1024, 256, 256, 204, 204, 1024};
  const int Ns[8]  = {256, 204, 32, 512, 512, 512, 1024, 1024};
  const int NRs[8] = {256, 256, 128, 512, 512, 512, 1024, 1024};
  const int KCs[8] = {1024, 1024, 1024, 256, 256, 224, 224, 1024};
  int total = 128 + 4096;
  for (int i = 0; i < 8; ++i) {
    p.src[i] = srcs[i]; p.dst[i] = dsts[i];
    p.K[i] = Ks[i]; p.N[i] = Ns[i]; p.NR[i] = NRs[i]; p.KC[i] = KCs[i];
    p.nb[i] = (KCs[i] / 32) * (NRs[i] / 32);
    total += p.nb[i];
  }
  p.cst = cst;
  p.xs[0] = x;  p.xs[1] = xf;
  p.xd[0] = x_bf; p.xd[1] = xf_bf;
  wprep_kernel<<<total, 256, 0, stream>>>(p);

  // 1) dual 64x128-tile GEMM (deep K=1024, exact 320 blocks): ql_f = x @ Wqc ;
  //    [kvl | kr] = xf @ [Wkvc | Wkr] (+rope/16)
  gemm_dualw1d<0, 4><<<320, 256, 0, stream>>>(
      x_bf, WqcT, ql_f, nullptr, 1024, 256, 2, 128,
      xf_bf, WkvkrT, kvl_f, kr_bf, 1024, 384, 3, cst);
  // 2) merged LN (1 row/wave, vectorized, no barriers)
  ln_fast_kernel<<<2048, 256, 0, stream>>>(ql_f, kvl_f, gq, bq, gkv, bkv, ql_bf, kvl_bf);
  // 3) dual 128-tile GEMM (short K, wide N, exact 640 blocks): [qn|qr] ; [kn|vT]
  gemm_dual1d<3, false, 5, false><<<640, 256, 0, stream>>>(
      ql_bf, WqnqrT, qn_bf, qr_bf, 256, 1024, 8, 256,
      kvl_bf, WknvT, kn_bf, vT_bf, 224, 1536, 12, cst);
  // 4) attention -> o bf16 (r3/r6/r8 config: t-tile 128, KVBLK 64, 2 blocks/CU)
  attn_mfma_kernel<<<512, 256, 0, stream>>>(qn_bf, qr_bf, kn_bf, kr_bf, vT_bf, o_bf);
  // 5) out = o @ Wo + bo (fp32), 64x128-tile deep-K: 512 blocks = 2/CU
  gemm_widek<1><<<dim3(8, 64), 256, 0, stream>>>(o_bf, WoT, bo, cst, out, nullptr, 1024, 1024);
}

// Round 10
// 208.269 us; speedup vs baseline: 1.3122x; 1.0004x over previous
//
#include <hip/hip_runtime.h>
#include <hip/hip_bf16.h>
#include <math.h>

#define SEQ 2048

typedef __bf16 bf16x8 __attribute__((ext_vector_type(8)));
typedef float  f32x4  __attribute__((ext_vector_type(4)));

#if __has_builtin(__builtin_amdgcn_exp2f)
#define EXP2(x) __builtin_amdgcn_exp2f(x)
#else
#define EXP2(x) exp2f(x)
#endif

__device__ __forceinline__ unsigned short f2bf(float f) {
  __bf16 h = (__bf16)f;
  return __builtin_bit_cast(unsigned short, h);
}

__device__ __forceinline__ void gload16(const unsigned short* g, unsigned short* l) {
  __builtin_amdgcn_global_load_lds(
      (const __attribute__((address_space(1))) void*)g,
      (__attribute__((address_space(3))) void*)l, 16, 0, 0);
}

// packed f32->bf16 convert (RNE, same rounding as scalar (__bf16) cast)
__device__ __forceinline__ unsigned cvtpk(float lo, float hi) {
  unsigned r;
  asm("v_cvt_pk_bf16_f32 %0, %1, %2" : "=v"(r) : "v"(lo), "v"(hi));
  return r;
}
// a[32:63] <-> b[0:31]:  a' = [a_q0,a_q1,b_q0,b_q1], b' = [a_q2,a_q3,b_q2,b_q3]
__device__ __forceinline__ void plswap32(unsigned &a, unsigned &b) {
  asm("v_permlane32_swap_b32 %0, %1" : "+v"(a), "+v"(b));
}
// odd 16-rows of a <-> even 16-rows of b: a' = [a0,b0,a2,b2], b' = [a1,b1,a3,b3]
__device__ __forceinline__ void plswap16(unsigned &a, unsigned &b) {
  asm("v_permlane16_swap_b32 %0, %1" : "+v"(a), "+v"(b));
}

#define CLOG (0.125f * 1.44269504f)   // 1/sqrt(HD) * log2(e), folded into q

// ===== mega prep: rope table + x/xf f32->bf16 convert + 8 weight transposes =====
struct WPrep {
  const float* src[8];
  unsigned short* dst[8];
  int K[8], N[8], NR[8], KC[8], nb[8];
  float2* cst;
  const float* xs[2];
  unsigned short* xd[2];
};

__global__ __launch_bounds__(256) void wprep_kernel(WPrep p)
{
  __shared__ float tile[32][33];
  int bid = blockIdx.x;
  if (bid < 128) {                       // rope table: 32768 entries
    const int idx = bid * 256 + threadIdx.x;
    const int pos = idx >> 4, i = idx & 15;
    const float freq = EXP2(-(float)i * 0.8304820237f);
    const float ang = (float)pos * freq;
    p.cst[idx] = make_float2(cosf(ang), sinf(ang));
    return;
  }
  bid -= 128;
  if (bid < 4096) {                      // x/xf f32 -> bf16 (2048 blocks each)
    const int sel = bid >> 11;
    const long base = (long)(bid & 2047) * 2048 + threadIdx.x * 8;
    const float4 a = *(const float4*)&p.xs[sel][base];
    const float4 b = *(const float4*)&p.xs[sel][base + 4];
    ushort4 u0, u1;
    u0.x = f2bf(a.x); u0.y = f2bf(a.y); u0.z = f2bf(a.z); u0.w = f2bf(a.w);
    u1.x = f2bf(b.x); u1.y = f2bf(b.y); u1.z = f2bf(b.z); u1.w = f2bf(b.w);
    *(ushort4*)&p.xd[sel][base] = u0;
    *(ushort4*)&p.xd[sel][base + 4] = u1;
    return;
  }
  bid -= 4096;
  int di = 0;
  while (bid >= p.nb[di]) { bid -= p.nb[di]; ++di; }
  const float* src = p.src[di];
  unsigned short* dst = p.dst[di];
  const int K = p.K[di], N = p.N[di], KC = p.KC[di];
  const int nkx = KC >> 5;
  const int k0 = (bid % nkx) * 32, n0 = (bid / nkx) * 32;
  const int tx = threadIdx.x & 31, ty = threadIdx.x >> 5;
  for (int r = ty; r < 32; r += 8) {
    const int k = k0 + r, n = n0 + tx;
    tile[r][tx] = (k < K && n < N) ? src[(long)k * N + n] : 0.0f;
  }
  __syncthreads();
  for (int r = ty; r < 32; r += 8) {
    const int n = n0 + r, k = k0 + tx;
    dst[(long)n * KC + k] = f2bf(tile[tx][r]);
  }
}

// ============ 128-tile bf16 MFMA GEMM body (for wide-N, short-K GEMMs) ============
// EPI: 3 QROPE: cols<512 -> qn (*CLOG); cols>=512 rope -> qr (*CLOG)   [stride 512]
//      5 KNV:   cols<512 -> kn (stride 512); cols>=512 -> vT (B,H,64,S) via LDS transpose
template <int EPI, bool AF32>
__device__ __forceinline__ void gemm_body(
    unsigned short* smem,                     // 16896 shorts
    const void* __restrict__ Av, const unsigned short* __restrict__ BT,
    const float* __restrict__ bias, const float2* __restrict__ cst,
    void* __restrict__ C0v, void* __restrict__ C1v, int K, int N,
    int bx, int by)
{
  unsigned short* As = smem;               // [2][128*32]
  unsigned short* Bs = smem + 2 * 128 * 32;
  const int tid = threadIdx.x;
  const int w = tid >> 6, lane = tid & 63;
  const int ln16 = lane & 15, quad = lane >> 4;
  const int wm = (w >> 1) * 64, wn = (w & 1) * 64;
  const int m0 = by * 128, n0 = bx * 128;
  const int rr = tid >> 2, cc = (tid & 3) * 8;

  const unsigned short* A = (const unsigned short*)Av;

  auto stageB = [&](int ib, int k0) {
    gload16(&BT[(long)(n0 + rr)      * K + k0 + cc], &Bs[ib * 4096 + rr * 32 + cc]);
    gload16(&BT[(long)(n0 + 64 + rr) * K + k0 + cc], &Bs[ib * 4096 + (64 + rr) * 32 + cc]);
  };
  auto stageAbf = [&](int ib, int k0) {
    gload16(&A[(long)(m0 + rr)      * K + k0 + cc], &As[ib * 4096 + rr * 32 + cc]);
    gload16(&A[(long)(m0 + 64 + rr) * K + k0 + cc], &As[ib * 4096 + (64 + rr) * 32 + cc]);
  };

  f32x4 acc[4][4];
#pragma unroll
  for (int i = 0; i < 4; ++i)
#pragma unroll
    for (int j = 0; j < 4; ++j)
#pragma unroll
      for (int r = 0; r < 4; ++r) acc[i][j][r] = 0.0f;

  stageB(0, 0);
  stageAbf(0, 0);

  int ib = 0;
  for (int k0 = 0; k0 < K; k0 += 32, ib ^= 1) {
    __syncthreads();
    const int kn = k0 + 32;
    if (kn < K) { stageB(ib ^ 1, kn); stageAbf(ib ^ 1, kn); }
    bf16x8 fa[4], fb[4];
#pragma unroll
    for (int i = 0; i < 4; ++i) fa[i] = *(const bf16x8*)&As[ib * 4096 + (wm + i * 16 + ln16) * 32 + quad * 8];
#pragma unroll
    for (int j = 0; j < 4; ++j) fb[j] = *(const bf16x8*)&Bs[ib * 4096 + (wn + j * 16 + ln16) * 32 + quad * 8];
#pragma unroll
    for (int i = 0; i < 4; ++i)
#pragma unroll
      for (int j = 0; j < 4; ++j)
        acc[i][j] = __builtin_amdgcn_mfma_f32_16x16x32_bf16(fa[i], fb[j], acc[i][j], 0, 0, 0);
  }

  // ----- epilogues -----
  if (EPI == 5 && n0 >= 512) {
    // fused V transpose: acc tile (128 s-rows x 128 cols) -> vT (B,H,64,S) coalesced
    __syncthreads();
#pragma unroll
    for (int i = 0; i < 4; ++i) {
      const int rl = wm + i * 16 + quad * 4;
#pragma unroll
      for (int j = 0; j < 4; ++j) {
        const int cl = wn + j * 16 + ln16;
        ushort4 u;
        u.x = f2bf(acc[i][j][0]); u.y = f2bf(acc[i][j][1]);
        u.z = f2bf(acc[i][j][2]); u.w = f2bf(acc[i][j][3]);
        *(ushort4*)&smem[cl * 132 + rl] = u;
      }
    }
    __syncthreads();
    unsigned short* vT = (unsigned short*)C1v;
    const int b = m0 >> 11, sbase = m0 & (SEQ - 1);
    for (int q = tid; q < 128 * 16; q += 256) {
      const int cl = q >> 4, sch = (q & 15) * 8;
      bf16x8 val = *(const bf16x8*)&smem[cl * 132 + sch];
      const int c = (n0 - 512) + cl;
      const int hh = c >> 6, dd = c & 63;
      *(bf16x8*)&vT[((long)(b * 16 + hh) * 64 + dd) * SEQ + sbase + sch] = val;
    }
    return;
  }
#pragma unroll
  for (int i = 0; i < 4; ++i) {
    const int row0 = m0 + wm + i * 16 + quad * 4;
#pragma unroll
    for (int j = 0; j < 4; ++j) {
      const int col = n0 + wn + j * 16 + ln16;
      if (EPI == 3) {
        if (n0 < 512) {
          unsigned short* qn = (unsigned short*)C0v;
#pragma unroll
          for (int r = 0; r < 4; ++r) qn[(long)(row0 + r) * 512 + col] = f2bf(acc[i][j][r] * CLOG);
        } else {
          unsigned short* qr = (unsigned short*)C1v;
          const int c = col - 512;
          const int d = c & 31;
#pragma unroll
          for (int r = 0; r < 4; ++r) {
            const float v = acc[i][j][r];
            const float p = __shfl_xor(v, 1);
            const float2 t = cst[((row0 + r) & (SEQ - 1)) * 16 + (d >> 1)];
            const float o = ((d & 1) == 0) ? (v * t.x - p * t.y) : (p * t.y + v * t.x);
            qr[(long)(row0 + r) * 512 + c] = f2bf(o * CLOG);
          }
        }
      } else if (EPI == 5) {
        unsigned short* kn = (unsigned short*)C0v;
#pragma unroll
        for (int r = 0; r < 4; ++r) kn[(long)(row0 + r) * 512 + col] = f2bf(acc[i][j][r]);
      }
    }
  }
}

// dual 128-tile wrapper, exact 1-D grid (no idle blocks)
template <int E0, bool AF0, int E1, bool AF1>
__global__ __launch_bounds__(256) void gemm_dual1d(
    const void* __restrict__ A0, const unsigned short* __restrict__ BT0,
    void* __restrict__ C00, void* __restrict__ C01, int K0, int N0, int nx0, int nb0,
    const void* __restrict__ A1, const unsigned short* __restrict__ BT1,
    void* __restrict__ C10, void* __restrict__ C11, int K1, int N1, int nx1,
    const float2* __restrict__ cst)
{
  __shared__ unsigned short smem[16896];
  int bid = blockIdx.x;
  if (bid < nb0) {
    gemm_body<E0, AF0>(smem, A0, BT0, nullptr, cst, C00, C01, K0, N0, bid % nx0, bid / nx0);
  } else {
    bid -= nb0;
    gemm_body<E1, AF1>(smem, A1, BT1, nullptr, cst, C10, C11, K1, N1, bid % nx1, bid / nx1);
  }
}

// ============ 64x128-tile bf16 GEMM body (deep-K; 8 MFMA/K-step/wave) ==============
// EPI: 0 f32->C0 ; 1 f32+bias->C0 ; 4 KVKR: cols<256 f32->kvl ; cols 256..287 rope/16->kr
template <int EPI>
__device__ __forceinline__ void gemm_wbody(
    unsigned short* smem,                     // 12288 shorts
    const unsigned short* __restrict__ A, const unsigned short* __restrict__ BT,
    const float* __restrict__ bias, const float2* __restrict__ cst,
    void* __restrict__ C0v, void* __restrict__ C1v, int K, int N,
    int bx, int by)
{
  unsigned short* As = smem;               // [2][64*32]
  unsigned short* Bs = smem + 4096;        // [2][128*32]
  const int tid = threadIdx.x;
  const int w = tid >> 6, lane = tid & 63;
  const int ln16 = lane & 15, quad = lane >> 4;
  const int wm = (w >> 1) * 32, wn = (w & 1) * 64;
  const int m0 = by * 64, n0 = bx * 128;
  const int rr = tid >> 2, cc = (tid & 3) * 8;

  auto stageA = [&](int ib, int k0) {
    gload16(&A[(long)(m0 + rr) * K + k0 + cc], &As[ib * 2048 + rr * 32 + cc]);
  };
  auto stageB = [&](int ib, int k0) {
    gload16(&BT[(long)(n0 + rr)      * K + k0 + cc], &Bs[ib * 4096 + rr * 32 + cc]);
    gload16(&BT[(long)(n0 + 64 + rr) * K + k0 + cc], &Bs[ib * 4096 + (64 + rr) * 32 + cc]);
  };

  f32x4 acc[2][4];
#pragma unroll
  for (int i = 0; i < 2; ++i)
#pragma unroll
    for (int j = 0; j < 4; ++j)
#pragma unroll
      for (int r = 0; r < 4; ++r) acc[i][j][r] = 0.0f;

  stageA(0, 0);
  stageB(0, 0);

  int ib = 0;
  for (int k0 = 0; k0 < K; k0 += 32, ib ^= 1) {
    __syncthreads();
    const int kn = k0 + 32;
    if (kn < K) { stageA(ib ^ 1, kn); stageB(ib ^ 1, kn); }
    bf16x8 fa[2], fb[4];
#pragma unroll
    for (int i = 0; i < 2; ++i) fa[i] = *(const bf16x8*)&As[ib * 2048 + (wm + i * 16 + ln16) * 32 + quad * 8];
#pragma unroll
    for (int j = 0; j < 4; ++j) fb[j] = *(const bf16x8*)&Bs[ib * 4096 + (wn + j * 16 + ln16) * 32 + quad * 8];
#pragma unroll
    for (int i = 0; i < 2; ++i)
#pragma unroll
      for (int j = 0; j < 4; ++j)
        acc[i][j] = __builtin_amdgcn_mfma_f32_16x16x32_bf16(fa[i], fb[j], acc[i][j], 0, 0, 0);
  }

#pragma unroll
  for (int i = 0; i < 2; ++i) {
    const int row0 = m0 + wm + i * 16 + quad * 4;
#pragma unroll
    for (int j = 0; j < 4; ++j) {
      const int col = n0 + wn + j * 16 + ln16;
      if (EPI == 0 || EPI == 1) {
        float* C = (float*)C0v;
        const float bv = (EPI == 1) ? bias[col] : 0.0f;
#pragma unroll
        for (int r = 0; r < 4; ++r) C[(long)(row0 + r) * N + col] = acc[i][j][r] + bv;
      } else if (EPI == 4) {
        if (col < 256) {
          float* kvl = (float*)C0v;
#pragma unroll
          for (int r = 0; r < 4; ++r) kvl[(long)(row0 + r) * 256 + col] = acc[i][j][r];
        } else if (col < 288) {             // kr cols 256..287 (rope/16)
          unsigned short* kr = (unsigned short*)C1v;
          const int d = col - 256;          // 0..31
#pragma unroll
          for (int r = 0; r < 4; ++r) {
            const float v = acc[i][j][r];
            const float p = __shfl_xor(v, 1);
            const float2 t = cst[((row0 + r) & (SEQ - 1)) * 16 + (d >> 1)];
            const float o = ((d & 1) == 0) ? (v * t.x - p * t.y) : (p * t.y + v * t.x);
            kr[(long)(row0 + r) * 32 + d] = f2bf(o * 0.0625f);
          }
        }
      }
    }
  }
}

template <int EPI>
__global__ __launch_bounds__(256) void gemm_widek(
    const unsigned short* __restrict__ A, const unsigned short* __restrict__ BT,
    const float* __restrict__ bias, const float2* __restrict__ cst,
    void* __restrict__ C0, void* __restrict__ C1, int K, int N)
{
  __shared__ unsigned short smem[12288];
  gemm_wbody<EPI>(smem, A, BT, bias, cst, C0, C1, K, N, blockIdx.x, blockIdx.y);
}

// dual wide wrapper, exact 1-D grid (no idle blocks)
template <int E0, int E1>
__global__ __launch_bounds__(256) void gemm_dualw1d(
    const unsigned short* __restrict__ A0, const unsigned short* __restrict__ BT0,
    void* __restrict__ C00, void* __restrict__ C01, int K0, int N0, int nx0, int nb0,
    const unsigned short* __restrict__ A1, const unsigned short* __restrict__ BT1,
    void* __restrict__ C10, void* __restrict__ C11, int K1, int N1, int nx1,
    const float2* __restrict__ cst)
{
  __shared__ unsigned short smem[12288];
  int bid = blockIdx.x;
  if (bid < nb0) {
    gemm_wbody<E0>(smem, A0, BT0, nullptr, cst, C00, C01, K0, N0, bid % nx0, bid / nx0);
  } else {
    bid -= nb0;
    gemm_wbody<E1>(smem, A1, BT1, nullptr, cst, C10, C11, K1, N1, bid % nx1, bid / nx1);
  }
}

// ---- fast merged LayerNorm: 1 row per WAVE, 4 rows/block, no LDS/barriers --------
// rows 0..4095 -> ql (C=256), 4096..8191 -> kvl (C=204, padded to 224)
__global__ __launch_bounds__(256) void ln_fast_kernel(
    const float* __restrict__ Xq, const float* __restrict__ Xkv,
    const float* __restrict__ gq, const float* __restrict__ bq,
    const float* __restrict__ gkv, const float* __restrict__ bkv,
    unsigned short* __restrict__ Yq, unsigned short* __restrict__ Ykv)
{
  const int tid = threadIdx.x;
  const int wv = tid >> 6, lane = tid & 63;
  const int row0 = blockIdx.x * 4 + wv;          // 0..8191
  const bool isq = row0 < 4096;
  const int row = isq ? row0 : row0 - 4096;
  const float* X = isq ? Xq : Xkv;
  const float* g = isq ? gq : gkv;
  const float* b = isq ? bq : bkv;
  unsigned short* Y = isq ? Yq : Ykv;
  const int C = isq ? 256 : 204;                 // both divisible by 4
  const int Cp = isq ? 256 : 224;
  const int col = lane * 4;
  const bool valid = col < C;                    // whole-float4 validity (C%4==0)
  float4 v = make_float4(0.f, 0.f, 0.f, 0.f);
  if (valid) v = *(const float4*)&X[(long)row * 256 + col];
  float s1 = v.x + v.y + v.z + v.w;
  float s2 = v.x * v.x + v.y * v.y + v.z * v.z + v.w * v.w;
#pragma unroll
  for (int off = 1; off < 64; off <<= 1) {
    s1 += __shfl_xor(s1, off);
    s2 += __shfl_xor(s2, off);
  }
  const float mean = s1 / C;
  const float var  = s2 / C - mean * mean;
  const float rs = rsqrtf(var + 1e-5f);
  if (valid) {
    const float4 gv = *(const float4*)&g[col];
    const float4 bv = *(const float4*)&b[col];
    ushort4 u;
    u.x = f2bf((v.x - mean) * rs * gv.x + bv.x);
    u.y = f2bf((v.y - mean) * rs * gv.y + bv.y);
    u.z = f2bf((v.z - mean) * rs * gv.z + bv.z);
    u.w = f2bf((v.w - mean) * rs * gv.w + bv.w);
    *(ushort4*)&Y[(long)row * Cp + col] = u;
  } else if (col < Cp) {
    *(ushort4*)&Y[(long)row * Cp + col] = make_ushort4(0, 0, 0, 0);
  }
}

// -------- MFMA flash attention: t-tile 256, 8 waves/block, 1 block/CU ------------
// grid = 256 (= 1 block/CU), block 512. q pre-scaled by CLOG at projection.
// One block owns the whole CU: K/V staged ONCE per CU per s-tile (vs 2x at r9's
// 2-block config) -- halves staging instructions, ds_writes and barrier count per
// unit work. Each wave owns t-groups A (t0+w*16) and B (+128); K/V fragments read
// once feed both. P stays in registers via cvt_pk + permlane32/16_swap.
#define KSTR 36
#define VSTR 68
__global__ __launch_bounds__(512, 1) void attn_mfma_kernel(
    const unsigned short* __restrict__ qn, const unsigned short* __restrict__ qr,
    const unsigned short* __restrict__ kn, const unsigned short* __restrict__ kr,
    const unsigned short* __restrict__ vT, unsigned short* __restrict__ ob)
{
  __shared__ unsigned short Kn[2][64 * KSTR];
  __shared__ unsigned short Vs[2][64 * VSTR];   // Vs[d][s]
  const int id = blockIdx.x;
  const int xcd = id & 7, j = id >> 3;          // j in 0..31
  const int bh = xcd * 4 + (j & 3);             // all 8 tiles of bh on one XCD
  const int tile = j >> 2;                      // 0..7
  const int b = bh >> 4, h = bh & 15;
  const int t0 = tile * 256;
  const int tid = threadIdx.x;
  const int w = tid >> 6, lane = tid & 63;      // w in 0..7
  const int ln16 = lane & 15, quad = lane >> 4;
  const int trow = w * 16;                      // 0..112
  const long bT = (long)b * SEQ;

  // staging indices over 512 threads: V = 512 chunks (1/thread), K = 256 (tid<256)
  const int vdr = tid >> 3, vcc = (tid & 7) * 8;           // V: 64 d-rows x 8 chunks
  const int krow = tid >> 2, kc8 = (tid & 3) * 8;          // K: 64 rows x 4 chunks

  // Q fragments: group A = rows t0+trow, group B = rows t0+128+trow
  bf16x8 q0A = *(const bf16x8*)&qn[(bT + t0 + trow + ln16) * 512 + h * 32 + quad * 8];
  bf16x8 q1A = *(const bf16x8*)&qr[(bT + t0 + trow + ln16) * 512 + h * 32 + quad * 8];
  bf16x8 q0B = *(const bf16x8*)&qn[(bT + t0 + 128 + trow + ln16) * 512 + h * 32 + quad * 8];
  bf16x8 q1B = *(const bf16x8*)&qr[(bT + t0 + 128 + trow + ln16) * 512 + h * 32 + quad * 8];

  auto loadKV = [&](int s0, bf16x8& rk, bf16x8& rv) {
    rv = *(const bf16x8*)&vT[((long)bh * 64 + vdr) * SEQ + s0 + vcc];
    if (tid < 256) rk = *(const bf16x8*)&kn[(bT + s0 + krow) * 512 + h * 32 + kc8];
  };
  auto writeKV = [&](int ib, bf16x8 rk, bf16x8 rv) {
    *(bf16x8*)&Vs[ib][vdr * VSTR + vcc] = rv;
    if (tid < 256) *(bf16x8*)&Kn[ib][krow * KSTR + kc8] = rk;
  };
  // kr A-fragments straight from global (L2-hot: shared by all h of this b)
  auto loadKrF = [&](int s0, bf16x8* f) {
#pragma unroll
    for (int nt = 0; nt < 4; ++nt)
      f[nt] = *(const bf16x8*)&kr[(bT + s0 + nt * 16 + ln16) * 32 + quad * 8];
  };
  // P transform: sf (4x f32x4, swapped-QK layout) -> two bf16x8 PV A-fragments
  auto pxform = [&](const f32x4* sf, float& l_part, bf16x8& a0, bf16x8& a1) {
    float p[16];
#pragma unroll
    for (int nt = 0; nt < 4; ++nt)
#pragma unroll
      for (int r = 0; r < 4; ++r) {
        const float e = EXP2(sf[nt][r]);
        p[nt * 4 + r] = e;
        l_part += e;
      }
    unsigned u0 = cvtpk(p[0],  p[1]),  u1 = cvtpk(p[2],  p[3]);
    unsigned u2 = cvtpk(p[4],  p[5]),  u3 = cvtpk(p[6],  p[7]);
    unsigned u4 = cvtpk(p[8],  p[9]),  u5 = cvtpk(p[10], p[11]);
    unsigned u6 = cvtpk(p[12], p[13]), u7 = cvtpk(p[14], p[15]);
    plswap32(u0, u2); plswap16(u0, u2);
    plswap32(u1, u3); plswap16(u1, u3);
    plswap32(u4, u6); plswap16(u4, u6);
    plswap32(u5, u7); plswap16(u5, u7);
    const uint4 w0 = make_uint4(u0, u1, u2, u3);   // P[t=ln16][s = 8q .. 8q+7]
    const uint4 w1 = make_uint4(u4, u5, u6, u7);   // P[t=ln16][s = 32+8q .. +7]
    a0 = __builtin_bit_cast(bf16x8, w0);
    a1 = __builtin_bit_cast(bf16x8, w1);
  };

  bf16x8 ck, cv;
  bf16x8 nk, nv;
  bf16x8 ckr[4];
  loadKV(0, ck, cv);
  writeKV(0, ck, cv);
  loadKV(64, nk, nv);
  loadKrF(0, ckr);

  f32x4 o_acc[2][4];
#pragma unroll
  for (int g = 0; g < 2; ++g)
#pragma unroll
    for (int nt = 0; nt < 4; ++nt)
#pragma unroll
      for (int r = 0; r < 4; ++r) o_acc[g][nt][r] = 0.0f;
  float l_part[2] = {0.0f, 0.0f};      // per-lane partials, groups A/B

  int ib = 0;
  for (int s0 = 0; s0 < SEQ; s0 += 64, ib ^= 1) {
    __syncthreads();
    if (s0 + 64 < SEQ) {
      writeKV(ib ^ 1, nk, nv);
      if (s0 + 128 < SEQ) loadKV(s0 + 128, nk, nv);
    }

    // K fragments: read ONCE, feed both t-groups
    bf16x8 ka[4];
#pragma unroll
    for (int nt = 0; nt < 4; ++nt)
      ka[nt] = *(const bf16x8*)&Kn[ib][(nt * 16 + ln16) * KSTR + quad * 8];

    // S^T = K @ Q^T for both groups
    f32x4 sfA[4], sfB[4];
#pragma unroll
    for (int nt = 0; nt < 4; ++nt)
#pragma unroll
      for (int r = 0; r < 4; ++r) { sfA[nt][r] = 0.0f; sfB[nt][r] = 0.0f; }
#pragma unroll
    for (int nt = 0; nt < 4; ++nt) {
      sfA[nt] = __builtin_amdgcn_mfma_f32_16x16x32_bf16(ka[nt], q0A, sfA[nt], 0, 0, 0);
      sfA[nt] = __builtin_amdgcn_mfma_f32_16x16x32_bf16(ckr[nt], q1A, sfA[nt], 0, 0, 0);
    }
#pragma unroll
    for (int nt = 0; nt < 4; ++nt) {
      sfB[nt] = __builtin_amdgcn_mfma_f32_16x16x32_bf16(ka[nt], q0B, sfB[nt], 0, 0, 0);
      sfB[nt] = __builtin_amdgcn_mfma_f32_16x16x32_bf16(ckr[nt], q1B, sfB[nt], 0, 0, 0);
    }

    // ckr consumed: reload for next s-tile (L2-hot; latency hidden by softmax+PV)
    if (s0 + 64 < SEQ) loadKrF(s0 + 64, ckr);

    bf16x8 a0A, a1A, a0B, a1B;
    pxform(sfA, l_part[0], a0A, a1A);
    pxform(sfB, l_part[1], a0B, a1B);

    // O += P(16 x 64) @ V(64 x 64), V fragments read ONCE for both groups
#pragma unroll
    for (int nt = 0; nt < 4; ++nt) {
      bf16x8 v0 = *(const bf16x8*)&Vs[ib][(nt * 16 + ln16) * VSTR + quad * 8];
      o_acc[0][nt] = __builtin_amdgcn_mfma_f32_16x16x32_bf16(a0A, v0, o_acc[0][nt], 0, 0, 0);
      o_acc[1][nt] = __builtin_amdgcn_mfma_f32_16x16x32_bf16(a0B, v0, o_acc[1][nt], 0, 0, 0);
      bf16x8 v1 = *(const bf16x8*)&Vs[ib][(nt * 16 + ln16) * VSTR + 32 + quad * 8];
      o_acc[0][nt] = __builtin_amdgcn_mfma_f32_16x16x32_bf16(a1A, v1, o_acc[0][nt], 0, 0, 0);
      o_acc[1][nt] = __builtin_amdgcn_mfma_f32_16x16x32_bf16(a1B, v1, o_acc[1][nt], 0, 0, 0);
    }
  }

  // per-group cross-quad l reduction + output
#pragma unroll
  for (int g = 0; g < 2; ++g) {
    float l_i = l_part[g];
    l_i += __shfl_xor(l_i, 16);
    l_i += __shfl_xor(l_i, 32);
    const float lr = 1.0f / l_i;
    float lq[4];
#pragma unroll
    for (int r = 0; r < 4; ++r) lq[r] = __shfl(lr, quad * 4 + r);
#pragma unroll
    for (int r = 0; r < 4; ++r) {
      const long t = t0 + g * 128 + trow + quad * 4 + r;
      const long base = (bT + t) * 1024 + h * 64 + ln16;
#pragma unroll
      for (int nt = 0; nt < 4; ++nt)
        ob[base + nt * 16] = f2bf(o_acc[g][nt][r] * lq[r]);
    }
  }
}

extern "C" void kernel_launch(void* const* d_in, const int* in_sizes, int n_in,
                              void* d_out, int out_size, void* d_ws, size_t ws_size,
                              hipStream_t stream) {
  const float* x       = (const float*)d_in[0];
  const float* xf      = (const float*)d_in[1];
  const float* Wqc     = (const float*)d_in[2];
  const float* gq      = (const float*)d_in[3];
  const float* bq      = (const float*)d_in[4];
  const float* Wq_rope = (const float*)d_in[5];   // rope before nope in dict order
  const float* Wq_nope = (const float*)d_in[6];
  const float* Wkvc    = (const float*)d_in[7];
  const float* gkv     = (const float*)d_in[8];
  const float* bkv     = (const float*)d_in[9];
  const float* Wk_nope = (const float*)d_in[10];
  const float* Wv      = (const float*)d_in[11];
  const float* Wkr     = (const float*)d_in[12];
  const float* Wo      = (const float*)d_in[13];
  const float* bo      = (const float*)d_in[14];
  float* out = (float*)d_out;

  const long R = 4096;
  float* ws = (float*)d_ws;
  float* ql_f  = ws;                       // 4096 x 256 f32
  float* kvl_f = ql_f + R * 256;           // 4096 x 256 f32
  float2* cst  = (float2*)(kvl_f + R * 256);  // 2048 x 16 cos/sin pairs
  unsigned short* us = (unsigned short*)(cst + 2048 * 16);
  unsigned short* ql_bf  = us;  us += R * 256;
  unsigned short* kvl_bf = us;  us += R * 224;    // K-padded to 224
  unsigned short* qn_bf  = us;  us += R * 512;
  unsigned short* qr_bf  = us;  us += R * 512;
  unsigned short* kn_bf  = us;  us += R * 512;
  unsigned short* kr_bf  = us;  us += R * 32;
  unsigned short* vT_bf  = us;  us += R * 1024;   // (B,H,64,S)
  unsigned short* o_bf   = us;  us += R * 1024;
  unsigned short* x_bf   = us;  us += R * 1024;   // x as bf16
  unsigned short* xf_bf  = us;  us += R * 1024;   // xf as bf16
  unsigned short* WqcT   = us;  us += 256 * 1024;
  unsigned short* WkvkrT = us;  us += 384 * 1024; // [Wkvc^T pad256 | Wkr^T pad128]
  unsigned short* WqnqrT = us;  us += 1024 * 256; // [Wq_nope^T | Wq_rope^T]
  unsigned short* WknvT  = us;  us += 1536 * 224; // [Wk_nope^T | Wv^T], K pad 224
  unsigned short* WoT    = us;  us += 1024 * 1024;

  // 0) mega prep: rope table + x/xf bf16 convert + 8 weight transposes
  WPrep p;
  const float* srcs[8] = {Wqc, Wkvc, Wkr, Wq_nope, Wq_rope, Wk_nope, Wv, Wo};
  unsigned short* dsts[8] = {WqcT, WkvkrT, WkvkrT + 256 * 1024,
                             WqnqrT, WqnqrT + 512 * 256,
                             WknvT, WknvT + 512 * 224, WoT};
  const int Ks[8]  = {1024, 1024, 1024, 256, 256, 204, 204, 1024};
  const int Ns[8]  = {256, 204, 32, 512, 512, 512, 1024, 1024};
  const int NRs[8] = {256, 256, 128, 512, 512, 512, 1024, 1024};
  const int KCs[8] = {1024, 1024, 1024, 256, 256, 224, 224, 1024};
  int total = 128 + 4096;
  for (int i = 0; i < 8; ++i) {
    p.src[i] = srcs[i]; p.dst[i] = dsts[i];
    p.K[i] = Ks[i]; p.N[i] = Ns[i]; p.NR[i] = NRs[i]; p.KC[i] = KCs[i];
    p.nb[i] = (KCs[i] / 32) * (NRs[i] / 32);
    total += p.nb[i];
  }
  p.cst = cst;
  p.xs[0] = x;  p.xs[1] = xf;
  p.xd[0] = x_bf; p.xd[1] = xf_bf;
  wprep_kernel<<<total, 256, 0, stream>>>(p);

  // 1) dual 64x128-tile GEMM (deep K=1024, exact 320 blocks): ql_f = x @ Wqc ;
  //    [kvl | kr] = xf @ [Wkvc | Wkr] (+rope/16)
  gemm_dualw1d<0, 4><<<320, 256, 0, stream>>>(
      x_bf, WqcT, ql_f, nullptr, 1024, 256, 2, 128,
      xf_bf, WkvkrT, kvl_f, kr_bf, 1024, 384, 3, cst);
  // 2) merged LN (1 row/wave, vectorized, no barriers)
  ln_fast_kernel<<<2048, 256, 0, stream>>>(ql_f, kvl_f, gq, bq, gkv, bkv, ql_bf, kvl_bf);
  // 3) dual 128-tile GEMM (short K, wide N, exact 640 blocks): [qn|qr] ; [kn|vT]
  gemm_dual1d<3, false, 5, false><<<640, 256, 0, stream>>>(
      ql_bf, WqnqrT, qn_bf, qr_bf, 256, 1024, 8, 256,
      kvl_bf, WknvT, kn_bf, vT_bf, 224, 1536, 12, cst);
  // 4) attention -> o bf16 (t-tile 256, 8 waves/block, 1 block/CU)
  attn_mfma_kernel<<<256, 512, 0, stream>>>(qn_bf, qr_bf, kn_bf, kr_bf, vT_bf, o_bf);
  // 5) out = o @ Wo + bo (fp32), 64x128-tile deep-K: 512 blocks = 2/CU
  gemm_widek<1><<<dim3(8, 64), 256, 0, stream>>>(o_bf, WoT, bo, cst, out, nullptr, 1024, 1024);
}

// Round 12
// 208.259 us; speedup vs baseline: 1.3123x; 1.0000x over previous
//
#include <hip/hip_runtime.h>
#include <hip/hip_bf16.h>
#include <math.h>

#define SEQ 2048

typedef __bf16 bf16x8 __attribute__((ext_vector_type(8)));
typedef float  f32x4  __attribute__((ext_vector_type(4)));

#if __has_builtin(__builtin_amdgcn_exp2f)
#define EXP2(x) __builtin_amdgcn_exp2f(x)
#else
#define EXP2(x) exp2f(x)
#endif

__device__ __forceinline__ unsigned short f2bf(float f) {
  __bf16 h = (__bf16)f;
  return __builtin_bit_cast(unsigned short, h);
}

__device__ __forceinline__ void gload16(const unsigned short* g, unsigned short* l) {
  __builtin_amdgcn_global_load_lds(
      (const __attribute__((address_space(1))) void*)g,
      (__attribute__((address_space(3))) void*)l, 16, 0, 0);
}

// packed f32->bf16 convert (RNE, same rounding as scalar (__bf16) cast)
__device__ __forceinline__ unsigned cvtpk(float lo, float hi) {
  unsigned r;
  asm("v_cvt_pk_bf16_f32 %0, %1, %2" : "=v"(r) : "v"(lo), "v"(hi));
  return r;
}
// a[32:63] <-> b[0:31]:  a' = [a_q0,a_q1,b_q0,b_q1], b' = [a_q2,a_q3,b_q2,b_q3]
__device__ __forceinline__ void plswap32(unsigned &a, unsigned &b) {
  asm("v_permlane32_swap_b32 %0, %1" : "+v"(a), "+v"(b));
}
// odd 16-rows of a <-> even 16-rows of b: a' = [a0,b0,a2,b2], b' = [a1,b1,a3,b3]
__device__ __forceinline__ void plswap16(unsigned &a, unsigned &b) {
  asm("v_permlane16_swap_b32 %0, %1" : "+v"(a), "+v"(b));
}

#define CLOG (0.125f * 1.44269504f)   // 1/sqrt(HD) * log2(e), folded into q

// ===== mega prep: rope table + x/xf f32->bf16 convert + 8 weight transposes =====
struct WPrep {
  const float* src[8];
  unsigned short* dst[8];
  int K[8], N[8], NR[8], KC[8], nb[8];
  float2* cst;
  const float* xs[2];
  unsigned short* xd[2];
};

__global__ __launch_bounds__(256) void wprep_kernel(WPrep p)
{
  __shared__ float tile[32][33];
  int bid = blockIdx.x;
  if (bid < 128) {                       // rope table: 32768 entries
    const int idx = bid * 256 + threadIdx.x;
    const int pos = idx >> 4, i = idx & 15;
    const float freq = EXP2(-(float)i * 0.8304820237f);
    const float ang = (float)pos * freq;
    p.cst[idx] = make_float2(cosf(ang), sinf(ang));
    return;
  }
  bid -= 128;
  if (bid < 4096) {                      // x/xf f32 -> bf16 (2048 blocks each)
    const int sel = bid >> 11;
    const long base = (long)(bid & 2047) * 2048 + threadIdx.x * 8;
    const float4 a = *(const float4*)&p.xs[sel][base];
    const float4 b = *(const float4*)&p.xs[sel][base + 4];
    ushort4 u0, u1;
    u0.x = f2bf(a.x); u0.y = f2bf(a.y); u0.z = f2bf(a.z); u0.w = f2bf(a.w);
    u1.x = f2bf(b.x); u1.y = f2bf(b.y); u1.z = f2bf(b.z); u1.w = f2bf(b.w);
    *(ushort4*)&p.xd[sel][base] = u0;
    *(ushort4*)&p.xd[sel][base + 4] = u1;
    return;
  }
  bid -= 4096;
  int di = 0;
  while (bid >= p.nb[di]) { bid -= p.nb[di]; ++di; }
  const float* src = p.src[di];
  unsigned short* dst = p.dst[di];
  const int K = p.K[di], N = p.N[di], KC = p.KC[di];
  const int nkx = KC >> 5;
  const int k0 = (bid % nkx) * 32, n0 = (bid / nkx) * 32;
  const int tx = threadIdx.x & 31, ty = threadIdx.x >> 5;
  for (int r = ty; r < 32; r += 8) {
    const int k = k0 + r, n = n0 + tx;
    tile[r][tx] = (k < K && n < N) ? src[(long)k * N + n] : 0.0f;
  }
  __syncthreads();
  for (int r = ty; r < 32; r += 8) {
    const int n = n0 + r, k = k0 + tx;
    dst[(long)n * KC + k] = f2bf(tile[tx][r]);
  }
}

// ============ 128-tile bf16 MFMA GEMM body (for wide-N, short-K GEMMs) ============
// EPI: 3 QROPE: cols<512 -> qn (*CLOG); cols>=512 rope -> qr (*CLOG)   [stride 512]
//      5 KNV:   cols<512 -> kn (stride 512); cols>=512 -> vT (B,H,64,S) via LDS transpose
template <int EPI, bool AF32>
__device__ __forceinline__ void gemm_body(
    unsigned short* smem,                     // 16896 shorts
    const void* __restrict__ Av, const unsigned short* __restrict__ BT,
    const float* __restrict__ bias, const float2* __restrict__ cst,
    void* __restrict__ C0v, void* __restrict__ C1v, int K, int N,
    int bx, int by)
{
  unsigned short* As = smem;               // [2][128*32]
  unsigned short* Bs = smem + 2 * 128 * 32;
  const int tid = threadIdx.x;
  const int w = tid >> 6, lane = tid & 63;
  const int ln16 = lane & 15, quad = lane >> 4;
  const int wm = (w >> 1) * 64, wn = (w & 1) * 64;
  const int m0 = by * 128, n0 = bx * 128;
  const int rr = tid >> 2, cc = (tid & 3) * 8;

  const unsigned short* A = (const unsigned short*)Av;

  auto stageB = [&](int ib, int k0) {
    gload16(&BT[(long)(n0 + rr)      * K + k0 + cc], &Bs[ib * 4096 + rr * 32 + cc]);
    gload16(&BT[(long)(n0 + 64 + rr) * K + k0 + cc], &Bs[ib * 4096 + (64 + rr) * 32 + cc]);
  };
  auto stageAbf = [&](int ib, int k0) {
    gload16(&A[(long)(m0 + rr)      * K + k0 + cc], &As[ib * 4096 + rr * 32 + cc]);
    gload16(&A[(long)(m0 + 64 + rr) * K + k0 + cc], &As[ib * 4096 + (64 + rr) * 32 + cc]);
  };

  f32x4 acc[4][4];
#pragma unroll
  for (int i = 0; i < 4; ++i)
#pragma unroll
    for (int j = 0; j < 4; ++j)
#pragma unroll
      for (int r = 0; r < 4; ++r) acc[i][j][r] = 0.0f;

  stageB(0, 0);
  stageAbf(0, 0);

  int ib = 0;
  for (int k0 = 0; k0 < K; k0 += 32, ib ^= 1) {
    __syncthreads();
    const int kn = k0 + 32;
    if (kn < K) { stageB(ib ^ 1, kn); stageAbf(ib ^ 1, kn); }
    bf16x8 fa[4], fb[4];
#pragma unroll
    for (int i = 0; i < 4; ++i) fa[i] = *(const bf16x8*)&As[ib * 4096 + (wm + i * 16 + ln16) * 32 + quad * 8];
#pragma unroll
    for (int j = 0; j < 4; ++j) fb[j] = *(const bf16x8*)&Bs[ib * 4096 + (wn + j * 16 + ln16) * 32 + quad * 8];
#pragma unroll
    for (int i = 0; i < 4; ++i)
#pragma unroll
      for (int j = 0; j < 4; ++j)
        acc[i][j] = __builtin_amdgcn_mfma_f32_16x16x32_bf16(fa[i], fb[j], acc[i][j], 0, 0, 0);
  }

  // ----- epilogues -----
  if (EPI == 5 && n0 >= 512) {
    // fused V transpose: acc tile (128 s-rows x 128 cols) -> vT (B,H,64,S) coalesced
    __syncthreads();
#pragma unroll
    for (int i = 0; i < 4; ++i) {
      const int rl = wm + i * 16 + quad * 4;
#pragma unroll
      for (int j = 0; j < 4; ++j) {
        const int cl = wn + j * 16 + ln16;
        ushort4 u;
        u.x = f2bf(acc[i][j][0]); u.y = f2bf(acc[i][j][1]);
        u.z = f2bf(acc[i][j][2]); u.w = f2bf(acc[i][j][3]);
        *(ushort4*)&smem[cl * 132 + rl] = u;
      }
    }
    __syncthreads();
    unsigned short* vT = (unsigned short*)C1v;
    const int b = m0 >> 11, sbase = m0 & (SEQ - 1);
    for (int q = tid; q < 128 * 16; q += 256) {
      const int cl = q >> 4, sch = (q & 15) * 8;
      bf16x8 val = *(const bf16x8*)&smem[cl * 132 + sch];
      const int c = (n0 - 512) + cl;
      const int hh = c >> 6, dd = c & 63;
      *(bf16x8*)&vT[((long)(b * 16 + hh) * 64 + dd) * SEQ + sbase + sch] = val;
    }
    return;
  }
#pragma unroll
  for (int i = 0; i < 4; ++i) {
    const int row0 = m0 + wm + i * 16 + quad * 4;
#pragma unroll
    for (int j = 0; j < 4; ++j) {
      const int col = n0 + wn + j * 16 + ln16;
      if (EPI == 3) {
        if (n0 < 512) {
          unsigned short* qn = (unsigned short*)C0v;
#pragma unroll
          for (int r = 0; r < 4; ++r) qn[(long)(row0 + r) * 512 + col] = f2bf(acc[i][j][r] * CLOG);
        } else {
          unsigned short* qr = (unsigned short*)C1v;
          const int c = col - 512;
          const int d = c & 31;
#pragma unroll
          for (int r = 0; r < 4; ++r) {
            const float v = acc[i][j][r];
            const float p = __shfl_xor(v, 1);
            const float2 t = cst[((row0 + r) & (SEQ - 1)) * 16 + (d >> 1)];
            const float o = ((d & 1) == 0) ? (v * t.x - p * t.y) : (p * t.y + v * t.x);
            qr[(long)(row0 + r) * 512 + c] = f2bf(o * CLOG);
          }
        }
      } else if (EPI == 5) {
        unsigned short* kn = (unsigned short*)C0v;
#pragma unroll
        for (int r = 0; r < 4; ++r) kn[(long)(row0 + r) * 512 + col] = f2bf(acc[i][j][r]);
      }
    }
  }
}

// dual 128-tile wrapper, exact 1-D grid (no idle blocks)
template <int E0, bool AF0, int E1, bool AF1>
__global__ __launch_bounds__(256) void gemm_dual1d(
    const void* __restrict__ A0, const unsigned short* __restrict__ BT0,
    void* __restrict__ C00, void* __restrict__ C01, int K0, int N0, int nx0, int nb0,
    const void* __restrict__ A1, const unsigned short* __restrict__ BT1,
    void* __restrict__ C10, void* __restrict__ C11, int K1, int N1, int nx1,
    const float2* __restrict__ cst)
{
  __shared__ unsigned short smem[16896];
  int bid = blockIdx.x;
  if (bid < nb0) {
    gemm_body<E0, AF0>(smem, A0, BT0, nullptr, cst, C00, C01, K0, N0, bid % nx0, bid / nx0);
  } else {
    bid -= nb0;
    gemm_body<E1, AF1>(smem, A1, BT1, nullptr, cst, C10, C11, K1, N1, bid % nx1, bid / nx1);
  }
}

// ============ 64x128-tile bf16 GEMM body (deep-K; 8 MFMA/K-step/wave) ==============
// EPI: 0 f32->C0 ; 1 f32+bias->C0 ; 4 KVKR: cols<256 f32->kvl ; cols 256..287 rope/16->kr
template <int EPI>
__device__ __forceinline__ void gemm_wbody(
    unsigned short* smem,                     // 12288 shorts
    const unsigned short* __restrict__ A, const unsigned short* __restrict__ BT,
    const float* __restrict__ bias, const float2* __restrict__ cst,
    void* __restrict__ C0v, void* __restrict__ C1v, int K, int N,
    int bx, int by)
{
  unsigned short* As = smem;               // [2][64*32]
  unsigned short* Bs = smem + 4096;        // [2][128*32]
  const int tid = threadIdx.x;
  const int w = tid >> 6, lane = tid & 63;
  const int ln16 = lane & 15, quad = lane >> 4;
  const int wm = (w >> 1) * 32, wn = (w & 1) * 64;
  const int m0 = by * 64, n0 = bx * 128;
  const int rr = tid >> 2, cc = (tid & 3) * 8;

  auto stageA = [&](int ib, int k0) {
    gload16(&A[(long)(m0 + rr) * K + k0 + cc], &As[ib * 2048 + rr * 32 + cc]);
  };
  auto stageB = [&](int ib, int k0) {
    gload16(&BT[(long)(n0 + rr)      * K + k0 + cc], &Bs[ib * 4096 + rr * 32 + cc]);
    gload16(&BT[(long)(n0 + 64 + rr) * K + k0 + cc], &Bs[ib * 4096 + (64 + rr) * 32 + cc]);
  };

  f32x4 acc[2][4];
#pragma unroll
  for (int i = 0; i < 2; ++i)
#pragma unroll
    for (int j = 0; j < 4; ++j)
#pragma unroll
      for (int r = 0; r < 4; ++r) acc[i][j][r] = 0.0f;

  stageA(0, 0);
  stageB(0, 0);

  int ib = 0;
  for (int k0 = 0; k0 < K; k0 += 32, ib ^= 1) {
    __syncthreads();
    const int kn = k0 + 32;
    if (kn < K) { stageA(ib ^ 1, kn); stageB(ib ^ 1, kn); }
    bf16x8 fa[2], fb[4];
#pragma unroll
    for (int i = 0; i < 2; ++i) fa[i] = *(const bf16x8*)&As[ib * 2048 + (wm + i * 16 + ln16) * 32 + quad * 8];
#pragma unroll
    for (int j = 0; j < 4; ++j) fb[j] = *(const bf16x8*)&Bs[ib * 4096 + (wn + j * 16 + ln16) * 32 + quad * 8];
#pragma unroll
    for (int i = 0; i < 2; ++i)
#pragma unroll
      for (int j = 0; j < 4; ++j)
        acc[i][j] = __builtin_amdgcn_mfma_f32_16x16x32_bf16(fa[i], fb[j], acc[i][j], 0, 0, 0);
  }

#pragma unroll
  for (int i = 0; i < 2; ++i) {
    const int row0 = m0 + wm + i * 16 + quad * 4;
#pragma unroll
    for (int j = 0; j < 4; ++j) {
      const int col = n0 + wn + j * 16 + ln16;
      if (EPI == 0 || EPI == 1) {
        float* C = (float*)C0v;
        const float bv = (EPI == 1) ? bias[col] : 0.0f;
#pragma unroll
        for (int r = 0; r < 4; ++r) C[(long)(row0 + r) * N + col] = acc[i][j][r] + bv;
      } else if (EPI == 4) {
        if (col < 256) {
          float* kvl = (float*)C0v;
#pragma unroll
          for (int r = 0; r < 4; ++r) kvl[(long)(row0 + r) * 256 + col] = acc[i][j][r];
        } else if (col < 288) {             // kr cols 256..287 (rope/16)
          unsigned short* kr = (unsigned short*)C1v;
          const int d = col - 256;          // 0..31
#pragma unroll
          for (int r = 0; r < 4; ++r) {
            const float v = acc[i][j][r];
            const float p = __shfl_xor(v, 1);
            const float2 t = cst[((row0 + r) & (SEQ - 1)) * 16 + (d >> 1)];
            const float o = ((d & 1) == 0) ? (v * t.x - p * t.y) : (p * t.y + v * t.x);
            kr[(long)(row0 + r) * 32 + d] = f2bf(o * 0.0625f);
          }
        }
      }
    }
  }
}

template <int EPI>
__global__ __launch_bounds__(256) void gemm_widek(
    const unsigned short* __restrict__ A, const unsigned short* __restrict__ BT,
    const float* __restrict__ bias, const float2* __restrict__ cst,
    void* __restrict__ C0, void* __restrict__ C1, int K, int N)
{
  __shared__ unsigned short smem[12288];
  gemm_wbody<EPI>(smem, A, BT, bias, cst, C0, C1, K, N, blockIdx.x, blockIdx.y);
}

// dual wide wrapper, exact 1-D grid (no idle blocks)
template <int E0, int E1>
__global__ __launch_bounds__(256) void gemm_dualw1d(
    const unsigned short* __restrict__ A0, const unsigned short* __restrict__ BT0,
    void* __restrict__ C00, void* __restrict__ C01, int K0, int N0, int nx0, int nb0,
    const unsigned short* __restrict__ A1, const unsigned short* __restrict__ BT1,
    void* __restrict__ C10, void* __restrict__ C11, int K1, int N1, int nx1,
    const float2* __restrict__ cst)
{
  __shared__ unsigned short smem[12288];
  int bid = blockIdx.x;
  if (bid < nb0) {
    gemm_wbody<E0>(smem, A0, BT0, nullptr, cst, C00, C01, K0, N0, bid % nx0, bid / nx0);
  } else {
    bid -= nb0;
    gemm_wbody<E1>(smem, A1, BT1, nullptr, cst, C10, C11, K1, N1, bid % nx1, bid / nx1);
  }
}

// ---- fast merged LayerNorm: 1 row per WAVE, 4 rows/block, no LDS/barriers --------
// rows 0..4095 -> ql (C=256), 4096..8191 -> kvl (C=204, padded to 224)
__global__ __launch_bounds__(256) void ln_fast_kernel(
    const float* __restrict__ Xq, const float* __restrict__ Xkv,
    const float* __restrict__ gq, const float* __restrict__ bq,
    const float* __restrict__ gkv, const float* __restrict__ bkv,
    unsigned short* __restrict__ Yq, unsigned short* __restrict__ Ykv)
{
  const int tid = threadIdx.x;
  const int wv = tid >> 6, lane = tid & 63;
  const int row0 = blockIdx.x * 4 + wv;          // 0..8191
  const bool isq = row0 < 4096;
  const int row = isq ? row0 : row0 - 4096;
  const float* X = isq ? Xq : Xkv;
  const float* g = isq ? gq : gkv;
  const float* b = isq ? bq : bkv;
  unsigned short* Y = isq ? Yq : Ykv;
  const int C = isq ? 256 : 204;                 // both divisible by 4
  const int Cp = isq ? 256 : 224;
  const int col = lane * 4;
  const bool valid = col < C;                    // whole-float4 validity (C%4==0)
  float4 v = make_float4(0.f, 0.f, 0.f, 0.f);
  if (valid) v = *(const float4*)&X[(long)row * 256 + col];
  float s1 = v.x + v.y + v.z + v.w;
  float s2 = v.x * v.x + v.y * v.y + v.z * v.z + v.w * v.w;
#pragma unroll
  for (int off = 1; off < 64; off <<= 1) {
    s1 += __shfl_xor(s1, off);
    s2 += __shfl_xor(s2, off);
  }
  const float mean = s1 / C;
  const float var  = s2 / C - mean * mean;
  const float rs = rsqrtf(var + 1e-5f);
  if (valid) {
    const float4 gv = *(const float4*)&g[col];
    const float4 bv = *(const float4*)&b[col];
    ushort4 u;
    u.x = f2bf((v.x - mean) * rs * gv.x + bv.x);
    u.y = f2bf((v.y - mean) * rs * gv.y + bv.y);
    u.z = f2bf((v.z - mean) * rs * gv.z + bv.z);
    u.w = f2bf((v.w - mean) * rs * gv.w + bv.w);
    *(ushort4*)&Y[(long)row * Cp + col] = u;
  } else if (col < Cp) {
    *(ushort4*)&Y[(long)row * Cp + col] = make_ushort4(0, 0, 0, 0);
  }
}

// -------- MFMA flash attention: t-tile 256, 8 waves/block, 1 block/CU ------------
// grid = 256 (= 1 block/CU), block 512. q pre-scaled by CLOG at projection.
// K/V staged once per CU per s-tile; each wave owns t-groups A (t0+w*16) and B
// (+128). Barrier is lgkm-only: ds ops drained, but the global register prefetches
// (nk/nv/ckr) legitimately stay in flight across it -- the compiler's vmcnt waits
// before their uses preserve correctness (reg-staged path; NOT legal for the
// global_load_lds GEMMs). P stays in registers via cvt_pk + permlane32/16_swap.
#define KSTR 36
#define VSTR 68
#define BAR_LGKM() asm volatile("s_waitcnt lgkmcnt(0)\n\ts_barrier" ::: "memory")
__global__ __launch_bounds__(512, 1) void attn_mfma_kernel(
    const unsigned short* __restrict__ qn, const unsigned short* __restrict__ qr,
    const unsigned short* __restrict__ kn, const unsigned short* __restrict__ kr,
    const unsigned short* __restrict__ vT, unsigned short* __restrict__ ob)
{
  __shared__ unsigned short Kn[2][64 * KSTR];
  __shared__ unsigned short Vs[2][64 * VSTR];   // Vs[d][s]
  const int id = blockIdx.x;
  const int xcd = id & 7, j = id >> 3;          // j in 0..31
  const int bh = xcd * 4 + (j & 3);             // all 8 tiles of bh on one XCD
  const int tile = j >> 2;                      // 0..7
  const int b = bh >> 4, h = bh & 15;
  const int t0 = tile * 256;
  const int tid = threadIdx.x;
  const int w = tid >> 6, lane = tid & 63;      // w in 0..7
  const int ln16 = lane & 15, quad = lane >> 4;
  const int trow = w * 16;                      // 0..112
  const long bT = (long)b * SEQ;

  // staging indices over 512 threads: V = 512 chunks (1/thread), K = 256 (tid<256)
  const int vdr = tid >> 3, vcc = (tid & 7) * 8;           // V: 64 d-rows x 8 chunks
  const int krow = tid >> 2, kc8 = (tid & 3) * 8;          // K: 64 rows x 4 chunks

  // Q fragments: group A = rows t0+trow, group B = rows t0+128+trow
  bf16x8 q0A = *(const bf16x8*)&qn[(bT + t0 + trow + ln16) * 512 + h * 32 + quad * 8];
  bf16x8 q1A = *(const bf16x8*)&qr[(bT + t0 + trow + ln16) * 512 + h * 32 + quad * 8];
  bf16x8 q0B = *(const bf16x8*)&qn[(bT + t0 + 128 + trow + ln16) * 512 + h * 32 + quad * 8];
  bf16x8 q1B = *(const bf16x8*)&qr[(bT + t0 + 128 + trow + ln16) * 512 + h * 32 + quad * 8];

  auto loadKV = [&](int s0, bf16x8& rk, bf16x8& rv) {
    rv = *(const bf16x8*)&vT[((long)bh * 64 + vdr) * SEQ + s0 + vcc];
    if (tid < 256) rk = *(const bf16x8*)&kn[(bT + s0 + krow) * 512 + h * 32 + kc8];
  };
  auto writeKV = [&](int ib, bf16x8 rk, bf16x8 rv) {
    *(bf16x8*)&Vs[ib][vdr * VSTR + vcc] = rv;
    if (tid < 256) *(bf16x8*)&Kn[ib][krow * KSTR + kc8] = rk;
  };
  // kr A-fragments straight from global (L2-hot: shared by all h of this b)
  auto loadKrF = [&](int s0, bf16x8* f) {
#pragma unroll
    for (int nt = 0; nt < 4; ++nt)
      f[nt] = *(const bf16x8*)&kr[(bT + s0 + nt * 16 + ln16) * 32 + quad * 8];
  };
  // P transform: sf (4x f32x4, swapped-QK layout) -> two bf16x8 PV A-fragments
  auto pxform = [&](const f32x4* sf, float& l_part, bf16x8& a0, bf16x8& a1) {
    float p[16];
#pragma unroll
    for (int nt = 0; nt < 4; ++nt)
#pragma unroll
      for (int r = 0; r < 4; ++r) {
        const float e = EXP2(sf[nt][r]);
        p[nt * 4 + r] = e;
        l_part += e;
      }
    unsigned u0 = cvtpk(p[0],  p[1]),  u1 = cvtpk(p[2],  p[3]);
    unsigned u2 = cvtpk(p[4],  p[5]),  u3 = cvtpk(p[6],  p[7]);
    unsigned u4 = cvtpk(p[8],  p[9]),  u5 = cvtpk(p[10], p[11]);
    unsigned u6 = cvtpk(p[12], p[13]), u7 = cvtpk(p[14], p[15]);
    plswap32(u0, u2); plswap16(u0, u2);
    plswap32(u1, u3); plswap16(u1, u3);
    plswap32(u4, u6); plswap16(u4, u6);
    plswap32(u5, u7); plswap16(u5, u7);
    const uint4 w0 = make_uint4(u0, u1, u2, u3);   // P[t=ln16][s = 8q .. 8q+7]
    const uint4 w1 = make_uint4(u4, u5, u6, u7);   // P[t=ln16][s = 32+8q .. +7]
    a0 = __builtin_bit_cast(bf16x8, w0);
    a1 = __builtin_bit_cast(bf16x8, w1);
  };

  bf16x8 ck, cv;
  bf16x8 nk, nv;
  bf16x8 ckr[4];
  loadKV(0, ck, cv);
  writeKV(0, ck, cv);
  loadKV(64, nk, nv);
  loadKrF(0, ckr);

  f32x4 o_acc[2][4];
#pragma unroll
  for (int g = 0; g < 2; ++g)
#pragma unroll
    for (int nt = 0; nt < 4; ++nt)
#pragma unroll
      for (int r = 0; r < 4; ++r) o_acc[g][nt][r] = 0.0f;
  float l_part[2] = {0.0f, 0.0f};      // per-lane partials, groups A/B

  int ib = 0;
  for (int s0 = 0; s0 < SEQ; s0 += 64, ib ^= 1) {
    BAR_LGKM();                        // ds drained; global prefetches stay in flight
    if (s0 + 64 < SEQ) {
      writeKV(ib ^ 1, nk, nv);
      if (s0 + 128 < SEQ) loadKV(s0 + 128, nk, nv);
    }

    // K fragments: read ONCE, feed both t-groups
    bf16x8 ka[4];
#pragma unroll
    for (int nt = 0; nt < 4; ++nt)
      ka[nt] = *(const bf16x8*)&Kn[ib][(nt * 16 + ln16) * KSTR + quad * 8];

    // S^T = K @ Q^T for both groups
    f32x4 sfA[4], sfB[4];
#pragma unroll
    for (int nt = 0; nt < 4; ++nt)
#pragma unroll
      for (int r = 0; r < 4; ++r) { sfA[nt][r] = 0.0f; sfB[nt][r] = 0.0f; }
#pragma unroll
    for (int nt = 0; nt < 4; ++nt) {
      sfA[nt] = __builtin_amdgcn_mfma_f32_16x16x32_bf16(ka[nt], q0A, sfA[nt], 0, 0, 0);
      sfA[nt] = __builtin_amdgcn_mfma_f32_16x16x32_bf16(ckr[nt], q1A, sfA[nt], 0, 0, 0);
    }
#pragma unroll
    for (int nt = 0; nt < 4; ++nt) {
      sfB[nt] = __builtin_amdgcn_mfma_f32_16x16x32_bf16(ka[nt], q0B, sfB[nt], 0, 0, 0);
      sfB[nt] = __builtin_amdgcn_mfma_f32_16x16x32_bf16(ckr[nt], q1B, sfB[nt], 0, 0, 0);
    }

    // ckr consumed: reload for next s-tile (L2-hot; latency hidden by softmax+PV)
    if (s0 + 64 < SEQ) loadKrF(s0 + 64, ckr);

    bf16x8 a0A, a1A, a0B, a1B;
    pxform(sfA, l_part[0], a0A, a1A);
    pxform(sfB, l_part[1], a0B, a1B);

    // O += P(16 x 64) @ V(64 x 64), V fragments read ONCE for both groups
#pragma unroll
    for (int nt = 0; nt < 4; ++nt) {
      bf16x8 v0 = *(const bf16x8*)&Vs[ib][(nt * 16 + ln16) * VSTR + quad * 8];
      o_acc[0][nt] = __builtin_amdgcn_mfma_f32_16x16x32_bf16(a0A, v0, o_acc[0][nt], 0, 0, 0);
      o_acc[1][nt] = __builtin_amdgcn_mfma_f32_16x16x32_bf16(a0B, v0, o_acc[1][nt], 0, 0, 0);
      bf16x8 v1 = *(const bf16x8*)&Vs[ib][(nt * 16 + ln16) * VSTR + 32 + quad * 8];
      o_acc[0][nt] = __builtin_amdgcn_mfma_f32_16x16x32_bf16(a1A, v1, o_acc[0][nt], 0, 0, 0);
      o_acc[1][nt] = __builtin_amdgcn_mfma_f32_16x16x32_bf16(a1B, v1, o_acc[1][nt], 0, 0, 0);
    }
  }

  // per-group cross-quad l reduction + output
#pragma unroll
  for (int g = 0; g < 2; ++g) {
    float l_i = l_part[g];
    l_i += __shfl_xor(l_i, 16);
    l_i += __shfl_xor(l_i, 32);
    const float lr = 1.0f / l_i;
    float lq[4];
#pragma unroll
    for (int r = 0; r < 4; ++r) lq[r] = __shfl(lr, quad * 4 + r);
#pragma unroll
    for (int r = 0; r < 4; ++r) {
      const long t = t0 + g * 128 + trow + quad * 4 + r;
      const long base = (bT + t) * 1024 + h * 64 + ln16;
#pragma unroll
      for (int nt = 0; nt < 4; ++nt)
        ob[base + nt * 16] = f2bf(o_acc[g][nt][r] * lq[r]);
    }
  }
}

extern "C" void kernel_launch(void* const* d_in, const int* in_sizes, int n_in,
                              void* d_out, int out_size, void* d_ws, size_t ws_size,
                              hipStream_t stream) {
  const float* x       = (const float*)d_in[0];
  const float* xf      = (const float*)d_in[1];
  const float* Wqc     = (const float*)d_in[2];
  const float* gq      = (const float*)d_in[3];
  const float* bq      = (const float*)d_in[4];
  const float* Wq_rope = (const float*)d_in[5];   // rope before nope in dict order
  const float* Wq_nope = (const float*)d_in[6];
  const float* Wkvc    = (const float*)d_in[7];
  const float* gkv     = (const float*)d_in[8];
  const float* bkv     = (const float*)d_in[9];
  const float* Wk_nope = (const float*)d_in[10];
  const float* Wv      = (const float*)d_in[11];
  const float* Wkr     = (const float*)d_in[12];
  const float* Wo      = (const float*)d_in[13];
  const float* bo      = (const float*)d_in[14];
  float* out = (float*)d_out;

  const long R = 4096;
  float* ws = (float*)d_ws;
  float* ql_f  = ws;                       // 4096 x 256 f32
  float* kvl_f = ql_f + R * 256;           // 4096 x 256 f32
  float2* cst  = (float2*)(kvl_f + R * 256);  // 2048 x 16 cos/sin pairs
  unsigned short* us = (unsigned short*)(cst + 2048 * 16);
  unsigned short* ql_bf  = us;  us += R * 256;
  unsigned short* kvl_bf = us;  us += R * 224;    // K-padded to 224
  unsigned short* qn_bf  = us;  us += R * 512;
  unsigned short* qr_bf  = us;  us += R * 512;
  unsigned short* kn_bf  = us;  us += R * 512;
  unsigned short* kr_bf  = us;  us += R * 32;
  unsigned short* vT_bf  = us;  us += R * 1024;   // (B,H,64,S)
  unsigned short* o_bf   = us;  us += R * 1024;
  unsigned short* x_bf   = us;  us += R * 1024;   // x as bf16
  unsigned short* xf_bf  = us;  us += R * 1024;   // xf as bf16
  unsigned short* WqcT   = us;  us += 256 * 1024;
  unsigned short* WkvkrT = us;  us += 384 * 1024; // [Wkvc^T pad256 | Wkr^T pad128]
  unsigned short* WqnqrT = us;  us += 1024 * 256; // [Wq_nope^T | Wq_rope^T]
  unsigned short* WknvT  = us;  us += 1536 * 224; // [Wk_nope^T | Wv^T], K pad 224
  unsigned short* WoT    = us;  us += 1024 * 1024;

  // 0) mega prep: rope table + x/xf bf16 convert + 8 weight transposes
  WPrep p;
  const float* srcs[8] = {Wqc, Wkvc, Wkr, Wq_nope, Wq_rope, Wk_nope, Wv, Wo};
  unsigned short* dsts[8] = {WqcT, WkvkrT, WkvkrT + 256 * 1024,
                             WqnqrT, WqnqrT + 512 * 256,
                             WknvT, WknvT + 512 * 224, WoT};
  const int Ks[8]  = {1024, 1024, 1024, 256, 256, 204, 204, 1024};
  const int Ns[8]  = {256, 204, 32, 512, 512, 512, 1024, 1024};
  const int NRs[8] = {256, 256, 128, 512, 512, 512, 1024, 1024};
  const int KCs[8] = {1024, 1024, 1024, 256, 256, 224, 224, 1024};
  int total = 128 + 4096;
  for (int i = 0; i < 8; ++i) {
    p.src[i] = srcs[i]; p.dst[i] = dsts[i];
    p.K[i] = Ks[i]; p.N[i] = Ns[i]; p.NR[i] = NRs[i]; p.KC[i] = KCs[i];
    p.nb[i] = (KCs[i] / 32) * (NRs[i] / 32);
    total += p.nb[i];
  }
  p.cst = cst;
  p.xs[0] = x;  p.xs[1] = xf;
  p.xd[0] = x_bf; p.xd[1] = xf_bf;
  wprep_kernel<<<total, 256, 0, stream>>>(p);

  // 1) dual 64x128-tile GEMM (deep K=1024, exact 320 blocks): ql_f = x @ Wqc ;
  //    [kvl | kr] = xf @ [Wkvc | Wkr] (+rope/16)
  gemm_dualw1d<0, 4><<<320, 256, 0, stream>>>(
      x_bf, WqcT, ql_f, nullptr, 1024, 256, 2, 128,
      xf_bf, WkvkrT, kvl_f, kr_bf, 1024, 384, 3, cst);
  // 2) merged LN (1 row/wave, vectorized, no barriers)
  ln_fast_kernel<<<2048, 256, 0, stream>>>(ql_f, kvl_f, gq, bq, gkv, bkv, ql_bf, kvl_bf);
  // 3) dual 128-tile GEMM (short K, wide N, exact 640 blocks): [qn|qr] ; [kn|vT]
  gemm_dual1d<3, false, 5, false><<<640, 256, 0, stream>>>(
      ql_bf, WqnqrT, qn_bf, qr_bf, 256, 1024, 8, 256,
      kvl_bf, WknvT, kn_bf, vT_bf, 224, 1536, 12, cst);
  // 4) attention -> o bf16 (t-tile 256, 1 block/CU, lgkm-only barrier)
  attn_mfma_kernel<<<256, 512, 0, stream>>>(qn_bf, qr_bf, kn_bf, kr_bf, vT_bf, o_bf);
  // 5) out = o @ Wo + bo (fp32), 64x128-tile deep-K: 512 blocks = 2/CU
  gemm_widek<1><<<dim3(8, 64), 256, 0, stream>>>(o_bf, WoT, bo, cst, out, nullptr, 1024, 1024);
}